// Round 8
// baseline (353.314 us; speedup 1.0000x reference)
//
#include <hip/hip_runtime.h>
#include <cmath>

using u16 = unsigned short;
using u32 = unsigned int;
using bf16x8 = __attribute__((ext_vector_type(8))) __bf16;
using f32x4  = __attribute__((ext_vector_type(4))) float;

__device__ inline u16 f2bf(float f) {
  u32 u = __float_as_uint(f);
  u32 r = (u + 0x7fffu + ((u >> 16) & 1u)) >> 16;  // RNE
  return (u16)r;
}

// ---------------- LayerNorm: x[row][1024] f32 -> xn bf16 ----------------
__global__ __launch_bounds__(256) void ln_kernel(
    const float* __restrict__ x, const float* __restrict__ w,
    const float* __restrict__ b, u16* __restrict__ xn) {
  int row = blockIdx.x;
  const float4* xr = (const float4*)(x + (size_t)row * 1024);
  float4 v = xr[threadIdx.x];
  float s  = v.x + v.y + v.z + v.w;
  float ss = v.x * v.x + v.y * v.y + v.z * v.z + v.w * v.w;
  int lane = threadIdx.x & 63, wave = threadIdx.x >> 6;
#pragma unroll
  for (int o = 32; o >= 1; o >>= 1) {
    s  += __shfl_xor(s, o, 64);
    ss += __shfl_xor(ss, o, 64);
  }
  __shared__ float rs[4], rq[4];
  if (lane == 0) { rs[wave] = s; rq[wave] = ss; }
  __syncthreads();
  s  = rs[0] + rs[1] + rs[2] + rs[3];
  ss = rq[0] + rq[1] + rq[2] + rq[3];
  float mean = s * (1.0f / 1024.0f);
  float var  = ss * (1.0f / 1024.0f) - mean * mean;
  float rstd = rsqrtf(var + 1e-5f);
  int c = threadIdx.x * 4;
  ushort4 ov;
  ov.x = f2bf((v.x - mean) * rstd * w[c + 0] + b[c + 0]);
  ov.y = f2bf((v.y - mean) * rstd * w[c + 1] + b[c + 1]);
  ov.z = f2bf((v.z - mean) * rstd * w[c + 2] + b[c + 2]);
  ov.w = f2bf((v.w - mean) * rstd * w[c + 3] + b[c + 3]);
  ((ushort4*)(xn + (size_t)row * 1024))[threadIdx.x] = ov;
}

// ---------------- weight transpose f32 [R][C] -> bf16 [C][R] ----------------
__global__ __launch_bounds__(256) void transpose_w(
    const float* __restrict__ in, u16* __restrict__ out, int R, int C) {
  __shared__ float tile[32][33];
  int c0 = blockIdx.x * 32, r0 = blockIdx.y * 32;
  int tx = threadIdx.x, ty = threadIdx.y;  // block (32,8)
#pragma unroll
  for (int i = 0; i < 32; i += 8)
    tile[ty + i][tx] = in[(size_t)(r0 + ty + i) * C + c0 + tx];
  __syncthreads();
#pragma unroll
  for (int i = 0; i < 32; i += 8)
    out[(size_t)(c0 + ty + i) * R + r0 + tx] = f2bf(tile[tx][ty + i]);
}

// ---------------- bias concat: bq|bk|bv -> bqkv[3072] ----------------
__global__ void concat_bias(const float* __restrict__ bq, const float* __restrict__ bk,
                            const float* __restrict__ bv, float* __restrict__ o) {
  int i = blockIdx.x * 1024 + threadIdx.x;
  const float* src = (blockIdx.x == 0) ? bq : (blockIdx.x == 1) ? bk : bv;
  o[i] = src[threadIdx.x];
}

// --------- rowinv: inv[bz][s] = 1 / sum_{tj >= s>>8} sumP[bz][tj][s] ---------
__global__ void rowinv_kernel(const float* __restrict__ sumP,
                              float* __restrict__ inv, int bA) {
  int r = blockIdx.x * 256 + threadIdx.x;
  int bz = bA + (r >> 11), s = r & 2047;
  float t = 0.f;
  for (int tj = s >> 8; tj < 8; ++tj)
    t += sumP[((size_t)bz * 8 + tj) * 2048 + s];
  inv[(size_t)bz * 2048 + s] = 1.0f / t;
}

// ---------------- BMx256 8-phase bf16 GEMM body, B^T layout ----------------
// C[M,N] = A[M,K] * Bt[N,K]^T. BK=64, 8 waves (2Mx4N), wave tile (BM/2)x64.
// R3-verified schedule: half-tiles in READ-ORDER, 1 half staged per phase,
// counted vmcnt at P4/P8 (BM=256: 6 in flight; BM=128: 5), VM0 tail.
// T2 st-swizzle both-sides, T5 setprio, explicit LGKM0 before MFMA.
// R8: geometry (LDA/LDB/LDC/KK/K0CT) compile-time; scale dropped for EPI=0.
// EPI 0: bf16 out (+bias). EPI 1: QK — E=exp(clamp(v)*scale-5), diag mask,
// bf16 store + per-row partial sums -> sumP. EPI 2: PV — f32 = acc*inv + bias.
template <int BM, int EPI, int LDA, int LDB, int LDC, int KK, int K0CT>
__device__ __forceinline__ void gemm_body(
    const u16* __restrict__ Ab, const u16* __restrict__ Bb,
    void* __restrict__ Cp, const float* __restrict__ bias,
    int rk0, float scale, size_t cbase, int ti, int tj,
    u16* __restrict__ AsP, u16* __restrict__ BsP,
    float* __restrict__ sumP, int diag, const float* __restrict__ invRow) {
  constexpr int WM = BM / 2;    // wave tile M
  constexpr int MH = BM / 64;   // m-frags per qm half
  constexpr int FM = 2 * MH;    // m-frags per wave
  constexpr int HR = BM / 4;    // rows per A read-order half
  constexpr int LA = BM / 128;  // GLLs per thread per A half

  const int k0 = (K0CT >= 0) ? K0CT : rk0;

  const int tid = threadIdx.x;
  const int wave = tid >> 6, lane = tid & 63;
  const int wr = wave >> 2, wc = wave & 3;  // 2 x 4 wave grid
  const int fr = lane & 15;
  const int kb16 = (lane >> 4) * 16;        // byte offset of k-frag in 64B k-block
  const int swz = (fr & 7) << 4;
  const int cs0 = kb16 ^ swz;               // ks=0 swizzled col byte
  const int cs1 = (64 + kb16) ^ swz;        // ks=1
  const int aRowOff = (wr * WM + fr) * 128;  // bytes
  const int bRowOff = (wc * 64 + fr) * 128;

  // Staging precompute (LD* compile-time -> shift addressing)
  size_t gAo[2][LA], gBo[2][2];
  u32 ldsA[2][LA], ldsB[2][2];
#pragma unroll
  for (int h = 0; h < 2; ++h) {
#pragma unroll
    for (int l = 0; l < LA; ++l) {
      int i = l * 512 + tid;
      int rih = i >> 3, ch8 = i & 7;
      int rA = (rih % HR) + (rih / HR) * WM + h * HR;
      int cbA = (ch8 << 4) ^ ((rA & 7) << 4);  // pre-swizzled source byte col
      gAo[h][l] = (size_t)rA * LDA + (cbA >> 1);
      ldsA[h][l] = (u32)(rA * 8 + ch8) * 16;
    }
#pragma unroll
    for (int l = 0; l < 2; ++l) {
      int i = l * 512 + tid;
      int rih = i >> 3, ch8 = i & 7;
      int rB = (rih & 31) + ((rih >> 5) << 6) + h * 32;
      int cbB = (ch8 << 4) ^ ((rB & 7) << 4);
      gBo[h][l] = (size_t)rB * LDB + (cbB >> 1);
      ldsB[h][l] = (u32)(rB * 8 + ch8) * 16;
    }
  }
  const size_t aBase = (size_t)(ti * BM) * LDA;
  const size_t bBase = (size_t)(tj * 256) * LDB;
  const int niter = (KK - k0) / 128;  // 2 K-tiles per iteration

  f32x4 acc[FM][4] = {};
  bf16x8 aF[MH][2], bF[4][2];

#define GLL(gaddr, laddr)                                        \
  __builtin_amdgcn_global_load_lds(                              \
      (const __attribute__((address_space(1))) void*)(gaddr),    \
      (__attribute__((address_space(3))) void*)(laddr), 16, 0, 0)

#define STAGE_A(buf, h, t)                                                   \
  do {                                                                       \
    const size_t _kt = aBase + (size_t)(k0 + (t) * 64);                      \
    _Pragma("unroll") for (int _l = 0; _l < LA; ++_l)                        \
        GLL(Ab + _kt + gAo[h][_l],                                           \
            (char*)(AsP + (buf) * (BM * 64)) + ldsA[h][_l]);                 \
  } while (0)
#define STAGE_B(buf, h, t)                                                   \
  do {                                                                       \
    const size_t _kt = bBase + (size_t)(k0 + (t) * 64);                      \
    _Pragma("unroll") for (int _l = 0; _l < 2; ++_l)                         \
        GLL(Bb + _kt + gBo[h][_l],                                           \
            (char*)(BsP + (buf) * (256 * 64)) + ldsB[h][_l]);                \
  } while (0)

#define DS_A(buf, qm)                                                        \
  do {                                                                       \
    const char* _pa =                                                        \
        (const char*)(AsP + (buf) * (BM * 64)) + aRowOff + (qm) * (MH * 2048); \
    _Pragma("unroll") for (int mm = 0; mm < MH; ++mm) {                      \
      aF[mm][0] = *(const bf16x8*)(_pa + mm * 2048 + cs0);                   \
      aF[mm][1] = *(const bf16x8*)(_pa + mm * 2048 + cs1);                   \
    }                                                                        \
  } while (0)
#define DS_B(buf, nh)                                                        \
  do {                                                                       \
    const char* _pb = (const char*)(BsP + (buf) * (256 * 64)) + bRowOff;     \
    _Pragma("unroll") for (int nn = 0; nn < 2; ++nn) {                       \
      bF[(nh)*2 + nn][0] = *(const bf16x8*)(_pb + ((nh)*2 + nn) * 2048 + cs0); \
      bF[(nh)*2 + nn][1] = *(const bf16x8*)(_pb + ((nh)*2 + nn) * 2048 + cs1); \
    }                                                                        \
  } while (0)

#define MMA(qm, nh)                                                          \
  do {                                                                       \
    _Pragma("unroll") for (int mm = 0; mm < MH; ++mm)                        \
    _Pragma("unroll") for (int nn = 0; nn < 2; ++nn) {                       \
      f32x4 _c = acc[(qm)*MH + mm][(nh)*2 + nn];                             \
      _c = __builtin_amdgcn_mfma_f32_16x16x32_bf16(aF[mm][0], bF[(nh)*2+nn][0], _c, 0, 0, 0); \
      _c = __builtin_amdgcn_mfma_f32_16x16x32_bf16(aF[mm][1], bF[(nh)*2+nn][1], _c, 0, 0, 0); \
      acc[(qm)*MH + mm][(nh)*2 + nn] = _c;                                   \
    }                                                                        \
  } while (0)

#define BAR __builtin_amdgcn_s_barrier()
#define LGKM0 asm volatile("s_waitcnt lgkmcnt(0)" ::: "memory")
#define VMN                                                                  \
  do {                                                                       \
    if constexpr (BM == 256)                                                 \
      asm volatile("s_waitcnt vmcnt(6)" ::: "memory");                       \
    else                                                                     \
      asm volatile("s_waitcnt vmcnt(5)" ::: "memory");                       \
  } while (0)
#define VM0 asm volatile("s_waitcnt vmcnt(0)" ::: "memory")
#define PRIO1 __builtin_amdgcn_s_setprio(1)
#define PRIO0 __builtin_amdgcn_s_setprio(0)

  // Prologue: tile0 all 4 halves (read-order) + tile1 B-h0,B-h1,A-h0.
  STAGE_B(0, 0, 0); STAGE_B(0, 1, 0); STAGE_A(0, 0, 0); STAGE_A(0, 1, 0);
  STAGE_B(1, 0, 1); STAGE_B(1, 1, 1); STAGE_A(1, 0, 1);
  VMN; BAR;  // tile0 fully landed; 3 half-tiles (tile1 B+A-h0) in flight

#pragma unroll 1
  for (int it = 0; it < niter; ++it) {
    const bool last = (it == niter - 1);
    const int t1g = 2 * it + 1, t2g = 2 * it + 2, t3g = 2 * it + 3;

    // ---- P1: read buf0 qm0+nh0; stage A-h1(t1g)->buf1
    DS_A(0, 0); DS_B(0, 0);
    STAGE_A(1, 1, t1g);
    BAR; LGKM0; PRIO1; MMA(0, 0); PRIO0; BAR;
    // ---- P2: read buf0 nh1; stage B-h0(t2g)->buf0
    DS_B(0, 1);
    if (!last) STAGE_B(0, 0, t2g);
    BAR; LGKM0; PRIO1; MMA(0, 1); PRIO0; BAR;
    // ---- P3: read buf0 qm1; stage B-h1(t2g)
    DS_A(0, 1);
    if (!last) STAGE_B(0, 1, t2g);
    BAR; LGKM0; PRIO1; MMA(1, 0); PRIO0; BAR;
    // ---- P4: stage A-h0(t2g); K-tile wait (lands ALL of tile t1g)
    if (!last) STAGE_A(0, 0, t2g);
    BAR; PRIO1; MMA(1, 1); PRIO0;
    if (last) { VM0; } else { VMN; }
    BAR;
    // ---- P5: read buf1 qm0+nh0; stage A-h1(t2g)
    DS_A(1, 0); DS_B(1, 0);
    if (!last) STAGE_A(0, 1, t2g);
    BAR; LGKM0; PRIO1; MMA(0, 0); PRIO0; BAR;
    // ---- P6: read buf1 nh1; stage B-h0(t3g)->buf1
    DS_B(1, 1);
    if (!last) STAGE_B(1, 0, t3g);
    BAR; LGKM0; PRIO1; MMA(0, 1); PRIO0; BAR;
    // ---- P7: read buf1 qm1; stage B-h1(t3g)
    DS_A(1, 1);
    if (!last) STAGE_B(1, 1, t3g);
    BAR; LGKM0; PRIO1; MMA(1, 0); PRIO0; BAR;
    // ---- P8: stage A-h0(t3g); K-tile wait (lands ALL of tile t2g)
    if (!last) STAGE_A(1, 0, t3g);
    BAR; PRIO1; MMA(1, 1); PRIO0;
    if (!last) VMN;
    BAR;
  }

  // Epilogue: C/D layout col=lane&15, row=(lane>>4)*4+j
  const int orow0 = ti * BM + wr * WM + ((lane >> 4) << 2);
  const int ocol0 = tj * 256 + wc * 64 + fr;

  if constexpr (EPI == 1) {
    // QK: E = exp(clamp(v)-5); diagonal mask; bf16 store; row partial sums.
    float* slds = (float*)AsP;  // [256][4] cross-wave reduce buffer
    const int rl0 = wr * WM + ((lane >> 4) << 2);
#pragma unroll
    for (int m = 0; m < FM; ++m) {
#pragma unroll
      for (int j = 0; j < 4; ++j) {
        const int rl = rl0 + m * 16 + j;
        const int row = ti * BM + rl;
        float rsum = 0.f;
#pragma unroll
        for (int n = 0; n < 4; ++n) {
          const int cl = wc * 64 + fr + n * 16;
          float v = acc[m][n][j] * scale;
          v = fminf(fmaxf(v, -1.0e9f), 1.0e9f);  // CLAMP
          v = fminf(v, 60.0f);                   // overflow guard
          float e = __expf(v - 5.0f);
          if (diag && cl < rl) e = 0.f;
          rsum += e;
          ((u16*)Cp)[cbase + (size_t)row * LDC + ocol0 + n * 16] = f2bf(e);
        }
        rsum += __shfl_xor(rsum, 1, 64);
        rsum += __shfl_xor(rsum, 2, 64);
        rsum += __shfl_xor(rsum, 4, 64);
        rsum += __shfl_xor(rsum, 8, 64);
        if (fr == 0) slds[rl * 4 + wc] = rsum;
      }
    }
    __syncthreads();
    if (tid < 256) {
      float t = slds[tid * 4 + 0] + slds[tid * 4 + 1] +
                slds[tid * 4 + 2] + slds[tid * 4 + 3];
      sumP[ti * BM + tid] = t;
    }
  } else {
#pragma unroll
    for (int m = 0; m < FM; ++m) {
#pragma unroll
      for (int j = 0; j < 4; ++j) {
        const int row = orow0 + m * 16 + j;
        float mul = (EPI == 2) ? invRow[row] : 1.0f;
#pragma unroll
        for (int n = 0; n < 4; ++n) {
          const int col = ocol0 + n * 16;
          const float bv = bias ? bias[col] : 0.0f;
          const size_t idx = cbase + (size_t)row * LDC + col;
          if constexpr (EPI == 2) {
            ((float*)Cp)[idx] = acc[m][n][j] * mul + bv;
          } else {
            ((u16*)Cp)[idx] = f2bf(acc[m][n][j] + bv);
          }
        }
      }
    }
  }
#undef GLL
#undef STAGE_A
#undef STAGE_B
#undef DS_A
#undef DS_B
#undef MMA
#undef BAR
#undef LGKM0
#undef VMN
#undef VM0
#undef PRIO1
#undef PRIO0
}

// ---------------- QKV projection (BM=256, all-CT geometry), XCD swizzle -----
__global__ __launch_bounds__(512, 2) void gemm_qkv(
    const u16* __restrict__ A, const u16* __restrict__ B, u16* __restrict__ Cv,
    const float* __restrict__ bias) {
  __shared__ u16 As[2][256 * 64];
  __shared__ u16 Bs[2][256 * 64];
  int wg = blockIdx.y * 12 + blockIdx.x;  // grid (12, 64)
  wg = (wg & 7) * 96 + (wg >> 3);         // bijective XCD swizzle (768 % 8 == 0)
  const int ti = wg / 12, tj = wg % 12;
  gemm_body<256, 0, 1024, 1024, 3072, 1024, 0>(
      A, B, Cv, bias, 0, 1.0f, 0, ti, tj, &As[0][0], &Bs[0][0],
      nullptr, 0, nullptr);
}

// ---------------- combined Wt + QK^T dispatch (both BM=256, CT geometry) ----
__global__ __launch_bounds__(512, 2) void gemm_qkwt(
    const u16* __restrict__ QKVp, const u16* __restrict__ w0t,
    u16* __restrict__ Wt, u16* __restrict__ sc, float* __restrict__ sumP,
    int wtBlocks, int b0, float qk_scale) {
  __shared__ u16 As[2][256 * 64];
  __shared__ u16 Bs[2][256 * 64];
  const long long sQKV = 2048LL * 3072, sWt = 1024LL * 2048, sS = 2048LL * 2048;
  int x = blockIdx.x;
  if (x < wtBlocks) {
    int r = x & 7, o = x >> 3;
    int ti = o & 3, bztj = r + 8 * (o >> 2);
    int bz = bztj >> 3, tj = bztj & 7;
    gemm_body<256, 0, 1024, 3072, 2048, 1024, 0>(
        w0t, QKVp + (size_t)bz * sQKV + 2048, Wt, nullptr, 0, 1.0f,
        (size_t)bz * sWt, ti, tj, &As[0][0], &Bs[0][0], nullptr, 0, nullptr);
  } else {
    int q = x - wtBlocks;
    int bz = b0 + q / 36, t36 = q % 36;
    int tj = 0, accm = 0;
    while (t36 >= accm + tj + 1) { accm += tj + 1; ++tj; }
    int tq = t36 - accm;
    const u16* Ab = QKVp + (size_t)bz * sQKV;
    gemm_body<256, 1, 3072, 3072, 2048, 1024, 0>(
        Ab, Ab + 1024, sc, nullptr, 0, qk_scale, (size_t)(bz - b0) * sS,
        tq, tj, &As[0][0], &Bs[0][0],
        sumP + ((size_t)bz * 8 + tj) * 2048, tq == tj, nullptr);
  }
}

// ---------------- PV dispatch (BM=128), LPT ti-major; EPI=2 normalize -------
__global__ __launch_bounds__(512, 2) void gemm_pv(
    const u16* __restrict__ sc, const u16* __restrict__ Wt,
    float* __restrict__ out, const float* __restrict__ b0v,
    const float* __restrict__ inv, int nb, int bA) {
  __shared__ u16 As[2][128 * 64];
  __shared__ u16 Bs[2][256 * 64];
  const long long sP = 2048LL * 2048, sWt = 1024LL * 2048, sH = 2048LL * 1024;
  int x = blockIdx.x;
  int g = 4 * nb;
  int ti = x / g, r = x % g;
  int bzl = r >> 2, tj = r & 3;
  int bz = bA + bzl;
  gemm_body<128, 2, 2048, 2048, 1024, 2048, -1>(
      sc + (size_t)bzl * sP, Wt + (size_t)bz * sWt, out, b0v, ti * 128, 1.0f,
      (size_t)bz * sH, ti, tj, &As[0][0], &Bs[0][0], nullptr, 0,
      inv + (size_t)bz * 2048);
}

extern "C" void kernel_launch(void* const* d_in, const int* in_sizes, int n_in,
                              void* d_out, int out_size, void* d_ws, size_t ws_size,
                              hipStream_t stream) {
  (void)in_sizes; (void)n_in; (void)out_size;
  const float* x   = (const float*)d_in[0];
  const float* lnw = (const float*)d_in[1];
  const float* lnb = (const float*)d_in[2];
  const float* wq  = (const float*)d_in[3];
  const float* bq  = (const float*)d_in[4];
  const float* wk  = (const float*)d_in[5];
  const float* bk  = (const float*)d_in[6];
  const float* wv  = (const float*)d_in[7];
  const float* bv  = (const float*)d_in[8];
  const float* w0  = (const float*)d_in[9];
  const float* b0  = (const float*)d_in[10];
  float* out = (float*)d_out;

  const size_t ROWS = 16384;  // B*S
  char* ws = (char*)d_ws;
  size_t off = 0;
  auto alloc = [&](size_t bytes) -> void* {
    void* p = ws + off;
    off += (bytes + 255) & ~(size_t)255;
    return p;
  };
  u16*   xn    = (u16*)alloc(ROWS * 1024 * 2);          // 32 MB
  u16*   wqkvt = (u16*)alloc((size_t)3072 * 1024 * 2);  // 6 MB
  u16*   w0t   = (u16*)alloc((size_t)1024 * 1024 * 2);  // 2 MB
  float* bqkv  = (float*)alloc(3072 * 4);
  float* sumP  = (float*)alloc((size_t)8 * 8 * 2048 * 4);  // 512 KB
  float* inv   = (float*)alloc((size_t)8 * 2048 * 4);      // 64 KB
  u16*   QKV   = (u16*)alloc(ROWS * 3072 * 2);          // ~100.7 MB
  u16*   Wt    = (u16*)alloc(ROWS * 1024 * 2);          // 32 MB [8][1024][2048]

  // scores (E bf16): NBCH batches of [2048 x 2048] per pass (8 MB each)
  const size_t CHUNK1 = (size_t)2048 * 2048 * 2;
  size_t avail = (ws_size > off) ? ws_size - off : 0;
  int NBCH = (int)(avail / CHUNK1);
  if (NBCH > 8) NBCH = 8;
  if (NBCH < 1) NBCH = 1;
  u16* sc = (u16*)(ws + off);

  ln_kernel<<<dim3(16384), dim3(256), 0, stream>>>(x, lnw, lnb, xn);
  dim3 tb(32, 8);
  transpose_w<<<dim3(32, 32), tb, 0, stream>>>(wq, wqkvt, 1024, 1024);
  transpose_w<<<dim3(32, 32), tb, 0, stream>>>(wk, wqkvt + (size_t)1024 * 1024, 1024, 1024);
  transpose_w<<<dim3(32, 32), tb, 0, stream>>>(wv, wqkvt + (size_t)2048 * 1024, 1024, 1024);
  transpose_w<<<dim3(32, 32), tb, 0, stream>>>(w0, w0t, 1024, 1024);
  concat_bias<<<dim3(3), dim3(1024), 0, stream>>>(bq, bk, bv, bqkv);

  // Fused QKV projection: [16384,1024] @ [1024,3072] -> QKV
  gemm_qkv<<<dim3(12, 64, 1), dim3(512), 0, stream>>>(xn, wqkvt, QKV, bqkv);

  float qk_scale = (float)(1.0 / (std::sqrt(1024.0) + 1e-9));

  for (int bA = 0; bA < 8; bA += NBCH) {
    int nb = 8 - bA;
    if (nb > NBCH) nb = NBCH;
    int wtB = (bA == 0) ? 256 : 0;  // Wt for ALL batches rides the first pass
    gemm_qkwt<<<dim3(wtB + nb * 36), dim3(512), 0, stream>>>(
        QKV, w0t, Wt, sc, sumP, wtB, bA, qk_scale);
    rowinv_kernel<<<dim3(nb * 8), dim3(256), 0, stream>>>(sumP, inv, bA);
    gemm_pv<<<dim3(64 * nb), dim3(512), 0, stream>>>(
        sc, Wt, out, b0, inv, nb, bA);
  }
}

// Round 9
// 343.897 us; speedup vs baseline: 1.0274x; 1.0274x over previous
//
#include <hip/hip_runtime.h>
#include <cmath>

using u16 = unsigned short;
using u32 = unsigned int;
using bf16x8 = __attribute__((ext_vector_type(8))) __bf16;
using f32x4  = __attribute__((ext_vector_type(4))) float;

__device__ inline u16 f2bf(float f) {
  u32 u = __float_as_uint(f);
  u32 r = (u + 0x7fffu + ((u >> 16) & 1u)) >> 16;  // RNE
  return (u16)r;
}

// ---------------- LayerNorm: x[row][1024] f32 -> xn bf16 ----------------
__global__ __launch_bounds__(256) void ln_kernel(
    const float* __restrict__ x, const float* __restrict__ w,
    const float* __restrict__ b, u16* __restrict__ xn) {
  int row = blockIdx.x;
  const float4* xr = (const float4*)(x + (size_t)row * 1024);
  float4 v = xr[threadIdx.x];
  float s  = v.x + v.y + v.z + v.w;
  float ss = v.x * v.x + v.y * v.y + v.z * v.z + v.w * v.w;
  int lane = threadIdx.x & 63, wave = threadIdx.x >> 6;
#pragma unroll
  for (int o = 32; o >= 1; o >>= 1) {
    s  += __shfl_xor(s, o, 64);
    ss += __shfl_xor(ss, o, 64);
  }
  __shared__ float rs[4], rq[4];
  if (lane == 0) { rs[wave] = s; rq[wave] = ss; }
  __syncthreads();
  s  = rs[0] + rs[1] + rs[2] + rs[3];
  ss = rq[0] + rq[1] + rq[2] + rq[3];
  float mean = s * (1.0f / 1024.0f);
  float var  = ss * (1.0f / 1024.0f) - mean * mean;
  float rstd = rsqrtf(var + 1e-5f);
  int c = threadIdx.x * 4;
  ushort4 ov;
  ov.x = f2bf((v.x - mean) * rstd * w[c + 0] + b[c + 0]);
  ov.y = f2bf((v.y - mean) * rstd * w[c + 1] + b[c + 1]);
  ov.z = f2bf((v.z - mean) * rstd * w[c + 2] + b[c + 2]);
  ov.w = f2bf((v.w - mean) * rstd * w[c + 3] + b[c + 3]);
  ((ushort4*)(xn + (size_t)row * 1024))[threadIdx.x] = ov;
}

// ---------------- weight transpose f32 [R][C] -> bf16 [C][R] ----------------
__global__ __launch_bounds__(256) void transpose_w(
    const float* __restrict__ in, u16* __restrict__ out, int R, int C) {
  __shared__ float tile[32][33];
  int c0 = blockIdx.x * 32, r0 = blockIdx.y * 32;
  int tx = threadIdx.x, ty = threadIdx.y;  // block (32,8)
#pragma unroll
  for (int i = 0; i < 32; i += 8)
    tile[ty + i][tx] = in[(size_t)(r0 + ty + i) * C + c0 + tx];
  __syncthreads();
#pragma unroll
  for (int i = 0; i < 32; i += 8)
    out[(size_t)(c0 + ty + i) * R + r0 + tx] = f2bf(tile[tx][ty + i]);
}

// ---------------- bias concat: bq|bk|bv -> bqkv[3072] ----------------
__global__ void concat_bias(const float* __restrict__ bq, const float* __restrict__ bk,
                            const float* __restrict__ bv, float* __restrict__ o) {
  int i = blockIdx.x * 1024 + threadIdx.x;
  const float* src = (blockIdx.x == 0) ? bq : (blockIdx.x == 1) ? bk : bv;
  o[i] = src[threadIdx.x];
}

// --------- rowinv: inv[bz][s] = 1 / sum_{tj >= s>>8} sumP[bz][tj][s] ---------
__global__ void rowinv_kernel(const float* __restrict__ sumP,
                              float* __restrict__ inv, int bA) {
  int r = blockIdx.x * 256 + threadIdx.x;
  int bz = bA + (r >> 11), s = r & 2047;
  float t = 0.f;
  for (int tj = s >> 8; tj < 8; ++tj)
    t += sumP[((size_t)bz * 8 + tj) * 2048 + s];
  inv[(size_t)bz * 2048 + s] = 1.0f / t;
}

// ---------------- BMx256 8-phase bf16 GEMM body, B^T layout ----------------
// C[M,N] = A[M,K] * Bt[N,K]^T. BK=64, 8 waves (2Mx4N), wave tile (BM/2)x64.
// R3-verified schedule: half-tiles in READ-ORDER, 1 half staged per phase,
// counted vmcnt at P4/P8 (BM=256: 6 in flight; BM=128: 5), VM0 tail.
// T2 st-swizzle both-sides, T5 setprio, explicit LGKM0 before MFMA.
// EPI 0: bf16 out (+bias). EPI 1: QK — E=exp(clamp(v)*scale-5), diag mask,
// bf16 store + per-row partial sums -> sumP. EPI 2: PV — f32 = acc*inv + bias.
template <int BM, int EPI, int LDA, int LDB, int LDC, int KK, int K0CT>
__device__ __forceinline__ void gemm_body(
    const u16* __restrict__ Ab, const u16* __restrict__ Bb,
    void* __restrict__ Cp, const float* __restrict__ bias,
    int rk0, float scale, size_t cbase, int ti, int tj,
    u16* __restrict__ AsP, u16* __restrict__ BsP,
    float* __restrict__ sumP, int diag, const float* __restrict__ invRow) {
  constexpr int WM = BM / 2;    // wave tile M
  constexpr int MH = BM / 64;   // m-frags per qm half
  constexpr int FM = 2 * MH;    // m-frags per wave
  constexpr int HR = BM / 4;    // rows per A read-order half
  constexpr int LA = BM / 128;  // GLLs per thread per A half

  const int k0 = (K0CT >= 0) ? K0CT : rk0;

  const int tid = threadIdx.x;
  const int wave = tid >> 6, lane = tid & 63;
  const int wr = wave >> 2, wc = wave & 3;  // 2 x 4 wave grid
  const int fr = lane & 15;
  const int kb16 = (lane >> 4) * 16;        // byte offset of k-frag in 64B k-block
  const int swz = (fr & 7) << 4;
  const int cs0 = kb16 ^ swz;               // ks=0 swizzled col byte
  const int cs1 = (64 + kb16) ^ swz;        // ks=1
  const int aRowOff = (wr * WM + fr) * 128;  // bytes
  const int bRowOff = (wc * 64 + fr) * 128;

  // Staging precompute
  size_t gAo[2][LA], gBo[2][2];
  u32 ldsA[2][LA], ldsB[2][2];
#pragma unroll
  for (int h = 0; h < 2; ++h) {
#pragma unroll
    for (int l = 0; l < LA; ++l) {
      int i = l * 512 + tid;
      int rih = i >> 3, ch8 = i & 7;
      int rA = (rih % HR) + (rih / HR) * WM + h * HR;
      int cbA = (ch8 << 4) ^ ((rA & 7) << 4);  // pre-swizzled source byte col
      gAo[h][l] = (size_t)rA * LDA + (cbA >> 1);
      ldsA[h][l] = (u32)(rA * 8 + ch8) * 16;
    }
#pragma unroll
    for (int l = 0; l < 2; ++l) {
      int i = l * 512 + tid;
      int rih = i >> 3, ch8 = i & 7;
      int rB = (rih & 31) + ((rih >> 5) << 6) + h * 32;
      int cbB = (ch8 << 4) ^ ((rB & 7) << 4);
      gBo[h][l] = (size_t)rB * LDB + (cbB >> 1);
      ldsB[h][l] = (u32)(rB * 8 + ch8) * 16;
    }
  }
  const size_t aBase = (size_t)(ti * BM) * LDA;
  const size_t bBase = (size_t)(tj * 256) * LDB;
  const int niter = (KK - k0) / 128;  // 2 K-tiles per iteration

  f32x4 acc[FM][4] = {};
  bf16x8 aF[MH][2], bF[4][2];

#define GLL(gaddr, laddr)                                        \
  __builtin_amdgcn_global_load_lds(                              \
      (const __attribute__((address_space(1))) void*)(gaddr),    \
      (__attribute__((address_space(3))) void*)(laddr), 16, 0, 0)

#define STAGE_A(buf, h, t)                                                   \
  do {                                                                       \
    const size_t _kt = aBase + (size_t)(k0 + (t) * 64);                      \
    _Pragma("unroll") for (int _l = 0; _l < LA; ++_l)                        \
        GLL(Ab + _kt + gAo[h][_l],                                           \
            (char*)(AsP + (buf) * (BM * 64)) + ldsA[h][_l]);                 \
  } while (0)
#define STAGE_B(buf, h, t)                                                   \
  do {                                                                       \
    const size_t _kt = bBase + (size_t)(k0 + (t) * 64);                      \
    _Pragma("unroll") for (int _l = 0; _l < 2; ++_l)                         \
        GLL(Bb + _kt + gBo[h][_l],                                           \
            (char*)(BsP + (buf) * (256 * 64)) + ldsB[h][_l]);                \
  } while (0)

#define DS_A(buf, qm)                                                        \
  do {                                                                       \
    const char* _pa =                                                        \
        (const char*)(AsP + (buf) * (BM * 64)) + aRowOff + (qm) * (MH * 2048); \
    _Pragma("unroll") for (int mm = 0; mm < MH; ++mm) {                      \
      aF[mm][0] = *(const bf16x8*)(_pa + mm * 2048 + cs0);                   \
      aF[mm][1] = *(const bf16x8*)(_pa + mm * 2048 + cs1);                   \
    }                                                                        \
  } while (0)
#define DS_B(buf, nh)                                                        \
  do {                                                                       \
    const char* _pb = (const char*)(BsP + (buf) * (256 * 64)) + bRowOff;     \
    _Pragma("unroll") for (int nn = 0; nn < 2; ++nn) {                       \
      bF[(nh)*2 + nn][0] = *(const bf16x8*)(_pb + ((nh)*2 + nn) * 2048 + cs0); \
      bF[(nh)*2 + nn][1] = *(const bf16x8*)(_pb + ((nh)*2 + nn) * 2048 + cs1); \
    }                                                                        \
  } while (0)

#define MMA(qm, nh)                                                          \
  do {                                                                       \
    _Pragma("unroll") for (int mm = 0; mm < MH; ++mm)                        \
    _Pragma("unroll") for (int nn = 0; nn < 2; ++nn) {                       \
      f32x4 _c = acc[(qm)*MH + mm][(nh)*2 + nn];                             \
      _c = __builtin_amdgcn_mfma_f32_16x16x32_bf16(aF[mm][0], bF[(nh)*2+nn][0], _c, 0, 0, 0); \
      _c = __builtin_amdgcn_mfma_f32_16x16x32_bf16(aF[mm][1], bF[(nh)*2+nn][1], _c, 0, 0, 0); \
      acc[(qm)*MH + mm][(nh)*2 + nn] = _c;                                   \
    }                                                                        \
  } while (0)

#define BAR __builtin_amdgcn_s_barrier()
#define LGKM0 asm volatile("s_waitcnt lgkmcnt(0)" ::: "memory")
#define VMN                                                                  \
  do {                                                                       \
    if constexpr (BM == 256)                                                 \
      asm volatile("s_waitcnt vmcnt(6)" ::: "memory");                       \
    else                                                                     \
      asm volatile("s_waitcnt vmcnt(5)" ::: "memory");                       \
  } while (0)
#define VM0 asm volatile("s_waitcnt vmcnt(0)" ::: "memory")
#define PRIO1 __builtin_amdgcn_s_setprio(1)
#define PRIO0 __builtin_amdgcn_s_setprio(0)

  // Prologue: tile0 all 4 halves (read-order) + tile1 B-h0,B-h1,A-h0.
  STAGE_B(0, 0, 0); STAGE_B(0, 1, 0); STAGE_A(0, 0, 0); STAGE_A(0, 1, 0);
  STAGE_B(1, 0, 1); STAGE_B(1, 1, 1); STAGE_A(1, 0, 1);
  VMN; BAR;  // tile0 fully landed; 3 half-tiles (tile1 B+A-h0) in flight

#pragma unroll 1
  for (int it = 0; it < niter; ++it) {
    const bool last = (it == niter - 1);
    const int t1g = 2 * it + 1, t2g = 2 * it + 2, t3g = 2 * it + 3;

    // ---- P1: read buf0 qm0+nh0; stage A-h1(t1g)->buf1
    DS_A(0, 0); DS_B(0, 0);
    STAGE_A(1, 1, t1g);
    BAR; LGKM0; PRIO1; MMA(0, 0); PRIO0; BAR;
    // ---- P2: read buf0 nh1; stage B-h0(t2g)->buf0
    DS_B(0, 1);
    if (!last) STAGE_B(0, 0, t2g);
    BAR; LGKM0; PRIO1; MMA(0, 1); PRIO0; BAR;
    // ---- P3: read buf0 qm1; stage B-h1(t2g)
    DS_A(0, 1);
    if (!last) STAGE_B(0, 1, t2g);
    BAR; LGKM0; PRIO1; MMA(1, 0); PRIO0; BAR;
    // ---- P4: stage A-h0(t2g); K-tile wait (lands ALL of tile t1g)
    if (!last) STAGE_A(0, 0, t2g);
    BAR; PRIO1; MMA(1, 1); PRIO0;
    if (last) { VM0; } else { VMN; }
    BAR;
    // ---- P5: read buf1 qm0+nh0; stage A-h1(t2g)
    DS_A(1, 0); DS_B(1, 0);
    if (!last) STAGE_A(0, 1, t2g);
    BAR; LGKM0; PRIO1; MMA(0, 0); PRIO0; BAR;
    // ---- P6: read buf1 nh1; stage B-h0(t3g)->buf1
    DS_B(1, 1);
    if (!last) STAGE_B(1, 0, t3g);
    BAR; LGKM0; PRIO1; MMA(0, 1); PRIO0; BAR;
    // ---- P7: read buf1 qm1; stage B-h1(t3g)
    DS_A(1, 1);
    if (!last) STAGE_B(1, 1, t3g);
    BAR; LGKM0; PRIO1; MMA(1, 0); PRIO0; BAR;
    // ---- P8: stage A-h0(t3g); K-tile wait (lands ALL of tile t2g)
    if (!last) STAGE_A(1, 0, t3g);
    BAR; PRIO1; MMA(1, 1); PRIO0;
    if (!last) VMN;
    BAR;
  }

  // Epilogue: C/D layout col=lane&15, row=(lane>>4)*4+j
  const int orow0 = ti * BM + wr * WM + ((lane >> 4) << 2);
  const int ocol0 = tj * 256 + wc * 64 + fr;

  if constexpr (EPI == 1) {
    // QK: E = exp(clamp(v)-5); diagonal mask; bf16 store; row partial sums.
    float* slds = (float*)AsP;  // [256][4] cross-wave reduce buffer
    const int rl0 = wr * WM + ((lane >> 4) << 2);
#pragma unroll
    for (int m = 0; m < FM; ++m) {
#pragma unroll
      for (int j = 0; j < 4; ++j) {
        const int rl = rl0 + m * 16 + j;
        const int row = ti * BM + rl;
        float rsum = 0.f;
#pragma unroll
        for (int n = 0; n < 4; ++n) {
          const int cl = wc * 64 + fr + n * 16;
          float v = acc[m][n][j] * scale;
          v = fminf(fmaxf(v, -1.0e9f), 1.0e9f);  // CLAMP
          v = fminf(v, 60.0f);                   // overflow guard
          float e = __expf(v - 5.0f);
          if (diag && cl < rl) e = 0.f;
          rsum += e;
          ((u16*)Cp)[cbase + (size_t)row * LDC + ocol0 + n * 16] = f2bf(e);
        }
        rsum += __shfl_xor(rsum, 1, 64);
        rsum += __shfl_xor(rsum, 2, 64);
        rsum += __shfl_xor(rsum, 4, 64);
        rsum += __shfl_xor(rsum, 8, 64);
        if (fr == 0) slds[rl * 4 + wc] = rsum;
      }
    }
    __syncthreads();
    if (tid < 256) {
      float t = slds[tid * 4 + 0] + slds[tid * 4 + 1] +
                slds[tid * 4 + 2] + slds[tid * 4 + 3];
      sumP[ti * BM + tid] = t;
    }
  } else {
#pragma unroll
    for (int m = 0; m < FM; ++m) {
#pragma unroll
      for (int j = 0; j < 4; ++j) {
        const int row = orow0 + m * 16 + j;
        float mul = (EPI == 2) ? invRow[row] : 1.0f;
#pragma unroll
        for (int n = 0; n < 4; ++n) {
          const int col = ocol0 + n * 16;
          const float bv = bias ? bias[col] : 0.0f;
          const size_t idx = cbase + (size_t)row * LDC + col;
          if constexpr (EPI == 2) {
            ((float*)Cp)[idx] = acc[m][n][j] * mul + bv;
          } else {
            ((u16*)Cp)[idx] = f2bf(acc[m][n][j] + bv);
          }
        }
      }
    }
  }
#undef GLL
#undef STAGE_A
#undef STAGE_B
#undef DS_A
#undef DS_B
#undef MMA
#undef BAR
#undef LGKM0
#undef VMN
#undef VM0
#undef PRIO1
#undef PRIO0
}

// ---------------- QKV projection (BM=256), per-XCD 16ti x 6tj panel ---------
// Each XCD owns a B-panel of 6 tj (3 MB < 4 MB L2); ti-fastest within XCD.
__global__ __launch_bounds__(512, 2) void gemm_qkv(
    const u16* __restrict__ A, const u16* __restrict__ B, u16* __restrict__ Cv,
    const float* __restrict__ bias) {
  __shared__ u16 As[2][256 * 64];
  __shared__ u16 Bs[2][256 * 64];
  int wg = blockIdx.x;               // 0..767, XCD = wg & 7 (round-robin)
  int xcd = wg & 7, idx = wg >> 3;   // 96 blocks per XCD
  int ti = ((xcd >> 1) << 4) + (idx & 15);
  int tj = (xcd & 1) * 6 + (idx >> 4);
  gemm_body<256, 0, 1024, 1024, 3072, 1024, 0>(
      A, B, Cv, bias, 0, 1.0f, 0, ti, tj, &As[0][0], &Bs[0][0],
      nullptr, 0, nullptr);
}

// ---------------- combined Wt + QK^T dispatch (both BM=256) -----------------
// QK part: batch -> XCD affinity (bzl = q % nb): per-XCD Q/K set = 1 batch.
__global__ __launch_bounds__(512, 2) void gemm_qkwt(
    const u16* __restrict__ QKVp, const u16* __restrict__ w0t,
    u16* __restrict__ Wt, u16* __restrict__ sc, float* __restrict__ sumP,
    int wtBlocks, int b0, int nb, float qk_scale) {
  __shared__ u16 As[2][256 * 64];
  __shared__ u16 Bs[2][256 * 64];
  const long long sQKV = 2048LL * 3072, sWt = 1024LL * 2048, sS = 2048LL * 2048;
  int x = blockIdx.x;
  if (x < wtBlocks) {
    int r = x & 7, o = x >> 3;
    int ti = o & 3, bztj = r + 8 * (o >> 2);
    int bz = bztj >> 3, tj = bztj & 7;
    gemm_body<256, 0, 1024, 3072, 2048, 1024, 0>(
        w0t, QKVp + (size_t)bz * sQKV + 2048, Wt, nullptr, 0, 1.0f,
        (size_t)bz * sWt, ti, tj, &As[0][0], &Bs[0][0], nullptr, 0, nullptr);
  } else {
    int q = x - wtBlocks;
    int bzl = q % nb, t36 = q / nb;
    int bz = b0 + bzl;
    int tj = 0, accm = 0;
    while (t36 >= accm + tj + 1) { accm += tj + 1; ++tj; }
    int tq = t36 - accm;
    const u16* Ab = QKVp + (size_t)bz * sQKV;
    gemm_body<256, 1, 3072, 3072, 2048, 1024, 0>(
        Ab, Ab + 1024, sc, nullptr, 0, qk_scale, (size_t)bzl * sS,
        tq, tj, &As[0][0], &Bs[0][0],
        sumP + ((size_t)bz * 8 + tj) * 2048, tq == tj, nullptr);
  }
}

// ---------------- PV dispatch (BM=128), batch->XCD + LPT ti-major -----------
__global__ __launch_bounds__(512, 2) void gemm_pv(
    const u16* __restrict__ sc, const u16* __restrict__ Wt,
    float* __restrict__ out, const float* __restrict__ b0v,
    const float* __restrict__ inv, int nb, int bA) {
  __shared__ u16 As[2][128 * 64];
  __shared__ u16 Bs[2][256 * 64];
  const long long sP = 2048LL * 2048, sWt = 1024LL * 2048, sH = 2048LL * 1024;
  int x = blockIdx.x;
  int bzl = x % nb;        // batch -> XCD affinity (Wt/P set per XCD)
  int rem = x / nb;        // 0..63, ascending ti = heavy blocks first (LPT)
  int ti = rem >> 2, tj = rem & 3;
  int bz = bA + bzl;
  gemm_body<128, 2, 2048, 2048, 1024, 2048, -1>(
      sc + (size_t)bzl * sP, Wt + (size_t)bz * sWt, out, b0v, ti * 128, 1.0f,
      (size_t)bz * sH, ti, tj, &As[0][0], &Bs[0][0], nullptr, 0,
      inv + (size_t)bz * 2048);
}

extern "C" void kernel_launch(void* const* d_in, const int* in_sizes, int n_in,
                              void* d_out, int out_size, void* d_ws, size_t ws_size,
                              hipStream_t stream) {
  (void)in_sizes; (void)n_in; (void)out_size;
  const float* x   = (const float*)d_in[0];
  const float* lnw = (const float*)d_in[1];
  const float* lnb = (const float*)d_in[2];
  const float* wq  = (const float*)d_in[3];
  const float* bq  = (const float*)d_in[4];
  const float* wk  = (const float*)d_in[5];
  const float* bk  = (const float*)d_in[6];
  const float* wv  = (const float*)d_in[7];
  const float* bv  = (const float*)d_in[8];
  const float* w0  = (const float*)d_in[9];
  const float* b0  = (const float*)d_in[10];
  float* out = (float*)d_out;

  const size_t ROWS = 16384;  // B*S
  char* ws = (char*)d_ws;
  size_t off = 0;
  auto alloc = [&](size_t bytes) -> void* {
    void* p = ws + off;
    off += (bytes + 255) & ~(size_t)255;
    return p;
  };
  u16*   xn    = (u16*)alloc(ROWS * 1024 * 2);          // 32 MB
  u16*   wqkvt = (u16*)alloc((size_t)3072 * 1024 * 2);  // 6 MB
  u16*   w0t   = (u16*)alloc((size_t)1024 * 1024 * 2);  // 2 MB
  float* bqkv  = (float*)alloc(3072 * 4);
  float* sumP  = (float*)alloc((size_t)8 * 8 * 2048 * 4);  // 512 KB
  float* inv   = (float*)alloc((size_t)8 * 2048 * 4);      // 64 KB
  u16*   QKV   = (u16*)alloc(ROWS * 3072 * 2);          // ~100.7 MB
  u16*   Wt    = (u16*)alloc(ROWS * 1024 * 2);          // 32 MB [8][1024][2048]

  // scores (E bf16): NBCH batches of [2048 x 2048] per pass (8 MB each)
  const size_t CHUNK1 = (size_t)2048 * 2048 * 2;
  size_t avail = (ws_size > off) ? ws_size - off : 0;
  int NBCH = (int)(avail / CHUNK1);
  if (NBCH > 8) NBCH = 8;
  if (NBCH < 1) NBCH = 1;
  u16* sc = (u16*)(ws + off);

  ln_kernel<<<dim3(16384), dim3(256), 0, stream>>>(x, lnw, lnb, xn);
  dim3 tb(32, 8);
  transpose_w<<<dim3(32, 32), tb, 0, stream>>>(wq, wqkvt, 1024, 1024);
  transpose_w<<<dim3(32, 32), tb, 0, stream>>>(wk, wqkvt + (size_t)1024 * 1024, 1024, 1024);
  transpose_w<<<dim3(32, 32), tb, 0, stream>>>(wv, wqkvt + (size_t)2048 * 1024, 1024, 1024);
  transpose_w<<<dim3(32, 32), tb, 0, stream>>>(w0, w0t, 1024, 1024);
  concat_bias<<<dim3(3), dim3(1024), 0, stream>>>(bq, bk, bv, bqkv);

  // Fused QKV projection: [16384,1024] @ [1024,3072] -> QKV
  gemm_qkv<<<dim3(768), dim3(512), 0, stream>>>(xn, wqkvt, QKV, bqkv);

  float qk_scale = (float)(1.0 / (std::sqrt(1024.0) + 1e-9));

  for (int bA = 0; bA < 8; bA += NBCH) {
    int nb = 8 - bA;
    if (nb > NBCH) nb = NBCH;
    int wtB = (bA == 0) ? 256 : 0;  // Wt for ALL batches rides the first pass
    gemm_qkwt<<<dim3(wtB + nb * 36), dim3(512), 0, stream>>>(
        QKV, w0t, Wt, sc, sumP, wtB, bA, nb, qk_scale);
    rowinv_kernel<<<dim3(nb * 8), dim3(256), 0, stream>>>(sumP, inv, bA);
    gemm_pv<<<dim3(64 * nb), dim3(512), 0, stream>>>(
        sc, Wt, out, b0, inv, nb, bA);
  }
}

// Round 10
// 325.348 us; speedup vs baseline: 1.0860x; 1.0570x over previous
//
#include <hip/hip_runtime.h>
#include <cmath>

using u16 = unsigned short;
using u32 = unsigned int;
using bf16x8 = __attribute__((ext_vector_type(8))) __bf16;
using f32x4  = __attribute__((ext_vector_type(4))) float;

__device__ inline u16 f2bf(float f) {
  u32 u = __float_as_uint(f);
  u32 r = (u + 0x7fffu + ((u >> 16) & 1u)) >> 16;  // RNE
  return (u16)r;
}

// ---------------- LayerNorm: x[row][1024] f32 -> xn bf16 ----------------
__global__ __launch_bounds__(256) void ln_kernel(
    const float* __restrict__ x, const float* __restrict__ w,
    const float* __restrict__ b, u16* __restrict__ xn) {
  int row = blockIdx.x;
  const float4* xr = (const float4*)(x + (size_t)row * 1024);
  float4 v = xr[threadIdx.x];
  float s  = v.x + v.y + v.z + v.w;
  float ss = v.x * v.x + v.y * v.y + v.z * v.z + v.w * v.w;
  int lane = threadIdx.x & 63, wave = threadIdx.x >> 6;
#pragma unroll
  for (int o = 32; o >= 1; o >>= 1) {
    s  += __shfl_xor(s, o, 64);
    ss += __shfl_xor(ss, o, 64);
  }
  __shared__ float rs[4], rq[4];
  if (lane == 0) { rs[wave] = s; rq[wave] = ss; }
  __syncthreads();
  s  = rs[0] + rs[1] + rs[2] + rs[3];
  ss = rq[0] + rq[1] + rq[2] + rq[3];
  float mean = s * (1.0f / 1024.0f);
  float var  = ss * (1.0f / 1024.0f) - mean * mean;
  float rstd = rsqrtf(var + 1e-5f);
  int c = threadIdx.x * 4;
  ushort4 ov;
  ov.x = f2bf((v.x - mean) * rstd * w[c + 0] + b[c + 0]);
  ov.y = f2bf((v.y - mean) * rstd * w[c + 1] + b[c + 1]);
  ov.z = f2bf((v.z - mean) * rstd * w[c + 2] + b[c + 2]);
  ov.w = f2bf((v.w - mean) * rstd * w[c + 3] + b[c + 3]);
  ((ushort4*)(xn + (size_t)row * 1024))[threadIdx.x] = ov;
}

// ---------------- weight transpose f32 [R][C] -> bf16 [C][R] ----------------
__global__ __launch_bounds__(256) void transpose_w(
    const float* __restrict__ in, u16* __restrict__ out, int R, int C) {
  __shared__ float tile[32][33];
  int c0 = blockIdx.x * 32, r0 = blockIdx.y * 32;
  int tx = threadIdx.x, ty = threadIdx.y;  // block (32,8)
#pragma unroll
  for (int i = 0; i < 32; i += 8)
    tile[ty + i][tx] = in[(size_t)(r0 + ty + i) * C + c0 + tx];
  __syncthreads();
#pragma unroll
  for (int i = 0; i < 32; i += 8)
    out[(size_t)(c0 + ty + i) * R + r0 + tx] = f2bf(tile[tx][ty + i]);
}

// ---------------- bias concat: bq|bk|bv -> bqkv[3072] ----------------
__global__ void concat_bias(const float* __restrict__ bq, const float* __restrict__ bk,
                            const float* __restrict__ bv, float* __restrict__ o) {
  int i = blockIdx.x * 1024 + threadIdx.x;
  const float* src = (blockIdx.x == 0) ? bq : (blockIdx.x == 1) ? bk : bv;
  o[i] = src[threadIdx.x];
}

// --------- rowinv: inv[bz][s] = 1 / sum_{tj >= s>>8} sumP[bz][tj][s] ---------
__global__ void rowinv_kernel(const float* __restrict__ sumP,
                              float* __restrict__ inv, int bA) {
  int r = blockIdx.x * 256 + threadIdx.x;
  int bz = bA + (r >> 11), s = r & 2047;
  float t = 0.f;
  for (int tj = s >> 8; tj < 8; ++tj)
    t += sumP[((size_t)bz * 8 + tj) * 2048 + s];
  inv[(size_t)bz * 2048 + s] = 1.0f / t;
}

// ============== R3-VERBATIM 256x256 8-phase bf16 GEMM (measured 118.7 us) ====
// Restored unchanged per rule #19 A/B: used ONLY for the QKV projection.
template <int OUTF32, int MODE>
__global__ __launch_bounds__(512, 2) void gemm256(
    const u16* __restrict__ A, const u16* __restrict__ B, void* __restrict__ Cv,
    const float* __restrict__ bias, int K, int lda, int ldb, int ldc,
    float scale, long long sA, long long sB, long long sC) {
  // XCD-aware bijective swizzle of (x,y) linear index
  int gx = gridDim.x;
  int wg = blockIdx.y * gx + blockIdx.x;
  {
    int nwg = gx * gridDim.y;
    if ((nwg & 7) == 0) {
      int q = nwg >> 3;
      wg = (wg & 7) * q + (wg >> 3);
    }
  }
  const int ti = wg / gx, tj = wg % gx, bz = blockIdx.z;
  if (MODE == 1 && tj < ti) return;  // fully-masked score tile

  const u16* Ab = A + (size_t)bz * (size_t)sA;
  const u16* Bb = B + (size_t)bz * (size_t)sB;

  __shared__ u16 As[2][256 * 64];  // 64 KiB
  __shared__ u16 Bs[2][256 * 64];  // 64 KiB

  const int tid = threadIdx.x;
  const int wave = tid >> 6, lane = tid & 63;
  const int wr = wave >> 2, wc = wave & 3;  // 2 x 4 wave grid
  const int fr = lane & 15;
  const int kb16 = (lane >> 4) * 16;        // byte offset of k-frag in 64B k-block
  const int swz = (fr & 7) << 4;
  const int cs0 = kb16 ^ swz;               // ks=0 swizzled col byte
  const int cs1 = (64 + kb16) ^ swz;        // ks=1
  const int aRowOff = (wr * 128 + fr) * 128;  // bytes
  const int bRowOff = (wc * 64 + fr) * 128;

  // Staging precompute: per (half h, l) -> global offset + LDS byte offset.
  size_t gAo[2][2], gBo[2][2];
  u32 ldsA[2][2], ldsB[2][2];
#pragma unroll
  for (int h = 0; h < 2; ++h) {
#pragma unroll
    for (int l = 0; l < 2; ++l) {
      int i = l * 512 + tid;
      int rih = i >> 3, ch8 = i & 7;
      // A: rows {0-63,128-191}+64h
      int rA = (rih & 63) + ((rih >> 6) << 7) + h * 64;
      int cbA = (ch8 << 4) ^ ((rA & 7) << 4);  // pre-swizzled source byte col
      gAo[h][l] = (size_t)rA * lda + (cbA >> 1);
      ldsA[h][l] = (u32)(rA * 8 + ch8) * 16;
      // B: rows {(r&63)<32}+32h
      int rB = (rih & 31) + ((rih >> 5) << 6) + h * 32;
      int cbB = (ch8 << 4) ^ ((rB & 7) << 4);
      gBo[h][l] = (size_t)rB * ldb + (cbB >> 1);
      ldsB[h][l] = (u32)(rB * 8 + ch8) * 16;
    }
  }
  const size_t aBase = (size_t)(ti * 256) * lda;
  const size_t bBase = (size_t)(tj * 256) * ldb;

  const int k0 = (MODE == 2) ? ti * 256 : 0;
  const int niter = (K - k0) / 128;  // 2 K-tiles per iteration

  f32x4 acc[8][4] = {};
  bf16x8 aF[4][2], bF[4][2];

#define GLL(gaddr, laddr)                                        \
  __builtin_amdgcn_global_load_lds(                              \
      (const __attribute__((address_space(1))) void*)(gaddr),    \
      (__attribute__((address_space(3))) void*)(laddr), 16, 0, 0)

#define STAGE_A(buf, h, t)                                                     \
  do {                                                                         \
    const size_t _kt = aBase + (size_t)(k0 + (t) * 64);                        \
    GLL(Ab + _kt + gAo[h][0], (char*)&As[buf][0] + ldsA[h][0]);                \
    GLL(Ab + _kt + gAo[h][1], (char*)&As[buf][0] + ldsA[h][1]);                \
  } while (0)
#define STAGE_B(buf, h, t)                                                     \
  do {                                                                         \
    const size_t _kt = bBase + (size_t)(k0 + (t) * 64);                        \
    GLL(Bb + _kt + gBo[h][0], (char*)&Bs[buf][0] + ldsB[h][0]);                \
    GLL(Bb + _kt + gBo[h][1], (char*)&Bs[buf][0] + ldsB[h][1]);                \
  } while (0)

#define DS_A(buf, qm)                                                \
  do {                                                               \
    const char* _pa = (const char*)&As[buf][0] + aRowOff + (qm)*8192;\
    _Pragma("unroll") for (int mm = 0; mm < 4; ++mm) {               \
      aF[mm][0] = *(const bf16x8*)(_pa + mm * 2048 + cs0);           \
      aF[mm][1] = *(const bf16x8*)(_pa + mm * 2048 + cs1);           \
    }                                                                \
  } while (0)
#define DS_B(buf, nh)                                                \
  do {                                                               \
    const char* _pb = (const char*)&Bs[buf][0] + bRowOff;            \
    _Pragma("unroll") for (int nn = 0; nn < 2; ++nn) {               \
      bF[(nh)*2 + nn][0] = *(const bf16x8*)(_pb + ((nh)*2 + nn) * 2048 + cs0); \
      bF[(nh)*2 + nn][1] = *(const bf16x8*)(_pb + ((nh)*2 + nn) * 2048 + cs1); \
    }                                                                \
  } while (0)

#define MMA(qm, nh)                                                          \
  do {                                                                       \
    _Pragma("unroll") for (int mm = 0; mm < 4; ++mm)                         \
    _Pragma("unroll") for (int nn = 0; nn < 2; ++nn) {                       \
      f32x4 _c = acc[(qm)*4 + mm][(nh)*2 + nn];                              \
      _c = __builtin_amdgcn_mfma_f32_16x16x32_bf16(aF[mm][0], bF[(nh)*2+nn][0], _c, 0, 0, 0); \
      _c = __builtin_amdgcn_mfma_f32_16x16x32_bf16(aF[mm][1], bF[(nh)*2+nn][1], _c, 0, 0, 0); \
      acc[(qm)*4 + mm][(nh)*2 + nn] = _c;                                    \
    }                                                                        \
  } while (0)

#define BAR __builtin_amdgcn_s_barrier()
#define LGKM0 asm volatile("s_waitcnt lgkmcnt(0)" ::: "memory")
#define VM6 asm volatile("s_waitcnt vmcnt(6)" ::: "memory")
#define VM0 asm volatile("s_waitcnt vmcnt(0)" ::: "memory")
#define PRIO1 __builtin_amdgcn_s_setprio(1)
#define PRIO0 __builtin_amdgcn_s_setprio(0)

  // Prologue: tile0 all 4 halves (read-order) + tile1 B-h0,B-h1,A-h0 = 14 ops.
  STAGE_B(0, 0, 0); STAGE_B(0, 1, 0); STAGE_A(0, 0, 0); STAGE_A(0, 1, 0);
  STAGE_B(1, 0, 1); STAGE_B(1, 1, 1); STAGE_A(1, 0, 1);
  VM6; BAR;  // tile0 fully landed; 3 half-tiles (tile1 B+A-h0) in flight

  for (int it = 0; it < niter; ++it) {
    const bool last = (it == niter - 1);
    const int t1g = 2 * it + 1, t2g = 2 * it + 2, t3g = 2 * it + 3;

    // ---- P1: read buf0 qm0+nh0; stage A-h1(t1g)->buf1
    DS_A(0, 0); DS_B(0, 0);
    STAGE_A(1, 1, t1g);
    BAR; LGKM0; PRIO1; MMA(0, 0); PRIO0; BAR;
    // ---- P2: read buf0 nh1; stage B-h0(t2g)->buf0 (nh0 reads done at P1 bar2)
    DS_B(0, 1);
    if (!last) STAGE_B(0, 0, t2g);
    BAR; LGKM0; PRIO1; MMA(0, 1); PRIO0; BAR;
    // ---- P3: read buf0 qm1; stage B-h1(t2g)
    DS_A(0, 1);
    if (!last) STAGE_B(0, 1, t2g);
    BAR; LGKM0; PRIO1; MMA(1, 0); PRIO0; BAR;
    // ---- P4: stage A-h0(t2g); K-tile wait (lands ALL of tile t1g)
    if (!last) STAGE_A(0, 0, t2g);
    BAR; PRIO1; MMA(1, 1); PRIO0;
    if (last) { VM0; } else { VM6; }
    BAR;
    // ---- P5: read buf1 qm0+nh0; stage A-h1(t2g)
    DS_A(1, 0); DS_B(1, 0);
    if (!last) STAGE_A(0, 1, t2g);
    BAR; LGKM0; PRIO1; MMA(0, 0); PRIO0; BAR;
    // ---- P6: read buf1 nh1; stage B-h0(t3g)->buf1
    DS_B(1, 1);
    if (!last) STAGE_B(1, 0, t3g);
    BAR; LGKM0; PRIO1; MMA(0, 1); PRIO0; BAR;
    // ---- P7: read buf1 qm1; stage B-h1(t3g)
    DS_A(1, 1);
    if (!last) STAGE_B(1, 1, t3g);
    BAR; LGKM0; PRIO1; MMA(1, 0); PRIO0; BAR;
    // ---- P8: stage A-h0(t3g); K-tile wait (lands ALL of tile t2g)
    if (!last) STAGE_A(1, 0, t3g);
    BAR; PRIO1; MMA(1, 1); PRIO0;
    if (!last) VM6;
    BAR;
  }

  // Epilogue: C/D layout col=lane&15, row=(lane>>4)*4+j
  const int orow0 = ti * 256 + wr * 128 + ((lane >> 4) << 2);
  const int ocol0 = tj * 256 + wc * 64 + fr;
#pragma unroll
  for (int m = 0; m < 8; ++m) {
#pragma unroll
    for (int n = 0; n < 4; ++n) {
      const int col = ocol0 + n * 16;
      const float bv = bias ? bias[col] : 0.0f;
#pragma unroll
      for (int j = 0; j < 4; ++j) {
        const int row = orow0 + m * 16 + j;
        const float v = acc[m][n][j] * scale + bv;
        const size_t idx = (size_t)bz * (size_t)sC + (size_t)row * ldc + col;
        if (OUTF32) ((float*)Cv)[idx] = v;
        else        ((u16*)Cv)[idx]   = f2bf(v);
      }
    }
  }
#undef GLL
#undef STAGE_A
#undef STAGE_B
#undef DS_A
#undef DS_B
#undef MMA
#undef BAR
#undef LGKM0
#undef VM6
#undef VM0
#undef PRIO1
#undef PRIO0
}

// ---------------- current BMx256 8-phase body (QK / Wt / PV paths) ----------
template <int BM, int EPI, int LDA, int LDB, int LDC, int KK, int K0CT>
__device__ __forceinline__ void gemm_body(
    const u16* __restrict__ Ab, const u16* __restrict__ Bb,
    void* __restrict__ Cp, const float* __restrict__ bias,
    int rk0, float scale, size_t cbase, int ti, int tj,
    u16* __restrict__ AsP, u16* __restrict__ BsP,
    float* __restrict__ sumP, int diag, const float* __restrict__ invRow) {
  constexpr int WM = BM / 2;    // wave tile M
  constexpr int MH = BM / 64;   // m-frags per qm half
  constexpr int FM = 2 * MH;    // m-frags per wave
  constexpr int HR = BM / 4;    // rows per A read-order half
  constexpr int LA = BM / 128;  // GLLs per thread per A half

  const int k0 = (K0CT >= 0) ? K0CT : rk0;

  const int tid = threadIdx.x;
  const int wave = tid >> 6, lane = tid & 63;
  const int wr = wave >> 2, wc = wave & 3;  // 2 x 4 wave grid
  const int fr = lane & 15;
  const int kb16 = (lane >> 4) * 16;        // byte offset of k-frag in 64B k-block
  const int swz = (fr & 7) << 4;
  const int cs0 = kb16 ^ swz;               // ks=0 swizzled col byte
  const int cs1 = (64 + kb16) ^ swz;        // ks=1
  const int aRowOff = (wr * WM + fr) * 128;  // bytes
  const int bRowOff = (wc * 64 + fr) * 128;

  // Staging precompute
  size_t gAo[2][LA], gBo[2][2];
  u32 ldsA[2][LA], ldsB[2][2];
#pragma unroll
  for (int h = 0; h < 2; ++h) {
#pragma unroll
    for (int l = 0; l < LA; ++l) {
      int i = l * 512 + tid;
      int rih = i >> 3, ch8 = i & 7;
      int rA = (rih % HR) + (rih / HR) * WM + h * HR;
      int cbA = (ch8 << 4) ^ ((rA & 7) << 4);  // pre-swizzled source byte col
      gAo[h][l] = (size_t)rA * LDA + (cbA >> 1);
      ldsA[h][l] = (u32)(rA * 8 + ch8) * 16;
    }
#pragma unroll
    for (int l = 0; l < 2; ++l) {
      int i = l * 512 + tid;
      int rih = i >> 3, ch8 = i & 7;
      int rB = (rih & 31) + ((rih >> 5) << 6) + h * 32;
      int cbB = (ch8 << 4) ^ ((rB & 7) << 4);
      gBo[h][l] = (size_t)rB * LDB + (cbB >> 1);
      ldsB[h][l] = (u32)(rB * 8 + ch8) * 16;
    }
  }
  const size_t aBase = (size_t)(ti * BM) * LDA;
  const size_t bBase = (size_t)(tj * 256) * LDB;
  const int niter = (KK - k0) / 128;  // 2 K-tiles per iteration

  f32x4 acc[FM][4] = {};
  bf16x8 aF[MH][2], bF[4][2];

#define GLL(gaddr, laddr)                                        \
  __builtin_amdgcn_global_load_lds(                              \
      (const __attribute__((address_space(1))) void*)(gaddr),    \
      (__attribute__((address_space(3))) void*)(laddr), 16, 0, 0)

#define STAGE_A(buf, h, t)                                                   \
  do {                                                                       \
    const size_t _kt = aBase + (size_t)(k0 + (t) * 64);                      \
    _Pragma("unroll") for (int _l = 0; _l < LA; ++_l)                        \
        GLL(Ab + _kt + gAo[h][_l],                                           \
            (char*)(AsP + (buf) * (BM * 64)) + ldsA[h][_l]);                 \
  } while (0)
#define STAGE_B(buf, h, t)                                                   \
  do {                                                                       \
    const size_t _kt = bBase + (size_t)(k0 + (t) * 64);                      \
    _Pragma("unroll") for (int _l = 0; _l < 2; ++_l)                         \
        GLL(Bb + _kt + gBo[h][_l],                                           \
            (char*)(BsP + (buf) * (256 * 64)) + ldsB[h][_l]);                \
  } while (0)

#define DS_A(buf, qm)                                                        \
  do {                                                                       \
    const char* _pa =                                                        \
        (const char*)(AsP + (buf) * (BM * 64)) + aRowOff + (qm) * (MH * 2048); \
    _Pragma("unroll") for (int mm = 0; mm < MH; ++mm) {                      \
      aF[mm][0] = *(const bf16x8*)(_pa + mm * 2048 + cs0);                   \
      aF[mm][1] = *(const bf16x8*)(_pa + mm * 2048 + cs1);                   \
    }                                                                        \
  } while (0)
#define DS_B(buf, nh)                                                        \
  do {                                                                       \
    const char* _pb = (const char*)(BsP + (buf) * (256 * 64)) + bRowOff;     \
    _Pragma("unroll") for (int nn = 0; nn < 2; ++nn) {                       \
      bF[(nh)*2 + nn][0] = *(const bf16x8*)(_pb + ((nh)*2 + nn) * 2048 + cs0); \
      bF[(nh)*2 + nn][1] = *(const bf16x8*)(_pb + ((nh)*2 + nn) * 2048 + cs1); \
    }                                                                        \
  } while (0)

#define MMA(qm, nh)                                                          \
  do {                                                                       \
    _Pragma("unroll") for (int mm = 0; mm < MH; ++mm)                        \
    _Pragma("unroll") for (int nn = 0; nn < 2; ++nn) {                       \
      f32x4 _c = acc[(qm)*MH + mm][(nh)*2 + nn];                             \
      _c = __builtin_amdgcn_mfma_f32_16x16x32_bf16(aF[mm][0], bF[(nh)*2+nn][0], _c, 0, 0, 0); \
      _c = __builtin_amdgcn_mfma_f32_16x16x32_bf16(aF[mm][1], bF[(nh)*2+nn][1], _c, 0, 0, 0); \
      acc[(qm)*MH + mm][(nh)*2 + nn] = _c;                                   \
    }                                                                        \
  } while (0)

#define BAR __builtin_amdgcn_s_barrier()
#define LGKM0 asm volatile("s_waitcnt lgkmcnt(0)" ::: "memory")
#define VMN                                                                  \
  do {                                                                       \
    if constexpr (BM == 256)                                                 \
      asm volatile("s_waitcnt vmcnt(6)" ::: "memory");                       \
    else                                                                     \
      asm volatile("s_waitcnt vmcnt(5)" ::: "memory");                       \
  } while (0)
#define VM0 asm volatile("s_waitcnt vmcnt(0)" ::: "memory")
#define PRIO1 __builtin_amdgcn_s_setprio(1)
#define PRIO0 __builtin_amdgcn_s_setprio(0)

  // Prologue: tile0 all 4 halves (read-order) + tile1 B-h0,B-h1,A-h0.
  STAGE_B(0, 0, 0); STAGE_B(0, 1, 0); STAGE_A(0, 0, 0); STAGE_A(0, 1, 0);
  STAGE_B(1, 0, 1); STAGE_B(1, 1, 1); STAGE_A(1, 0, 1);
  VMN; BAR;  // tile0 fully landed; 3 half-tiles (tile1 B+A-h0) in flight

#pragma unroll 1
  for (int it = 0; it < niter; ++it) {
    const bool last = (it == niter - 1);
    const int t1g = 2 * it + 1, t2g = 2 * it + 2, t3g = 2 * it + 3;

    // ---- P1: read buf0 qm0+nh0; stage A-h1(t1g)->buf1
    DS_A(0, 0); DS_B(0, 0);
    STAGE_A(1, 1, t1g);
    BAR; LGKM0; PRIO1; MMA(0, 0); PRIO0; BAR;
    // ---- P2: read buf0 nh1; stage B-h0(t2g)->buf0
    DS_B(0, 1);
    if (!last) STAGE_B(0, 0, t2g);
    BAR; LGKM0; PRIO1; MMA(0, 1); PRIO0; BAR;
    // ---- P3: read buf0 qm1; stage B-h1(t2g)
    DS_A(0, 1);
    if (!last) STAGE_B(0, 1, t2g);
    BAR; LGKM0; PRIO1; MMA(1, 0); PRIO0; BAR;
    // ---- P4: stage A-h0(t2g); K-tile wait (lands ALL of tile t1g)
    if (!last) STAGE_A(0, 0, t2g);
    BAR; PRIO1; MMA(1, 1); PRIO0;
    if (last) { VM0; } else { VMN; }
    BAR;
    // ---- P5: read buf1 qm0+nh0; stage A-h1(t2g)
    DS_A(1, 0); DS_B(1, 0);
    if (!last) STAGE_A(0, 1, t2g);
    BAR; LGKM0; PRIO1; MMA(0, 0); PRIO0; BAR;
    // ---- P6: read buf1 nh1; stage B-h0(t3g)->buf1
    DS_B(1, 1);
    if (!last) STAGE_B(1, 0, t3g);
    BAR; LGKM0; PRIO1; MMA(0, 1); PRIO0; BAR;
    // ---- P7: read buf1 qm1; stage B-h1(t3g)
    DS_A(1, 1);
    if (!last) STAGE_B(1, 1, t3g);
    BAR; LGKM0; PRIO1; MMA(1, 0); PRIO0; BAR;
    // ---- P8: stage A-h0(t3g); K-tile wait (lands ALL of tile t2g)
    if (!last) STAGE_A(1, 0, t3g);
    BAR; PRIO1; MMA(1, 1); PRIO0;
    if (!last) VMN;
    BAR;
  }

  // Epilogue: C/D layout col=lane&15, row=(lane>>4)*4+j
  const int orow0 = ti * BM + wr * WM + ((lane >> 4) << 2);
  const int ocol0 = tj * 256 + wc * 64 + fr;

  if constexpr (EPI == 1) {
    // QK: E = exp(clamp(v)-5); diagonal mask; bf16 store; row partial sums.
    float* slds = (float*)AsP;  // [256][4] cross-wave reduce buffer
    const int rl0 = wr * WM + ((lane >> 4) << 2);
#pragma unroll
    for (int m = 0; m < FM; ++m) {
#pragma unroll
      for (int j = 0; j < 4; ++j) {
        const int rl = rl0 + m * 16 + j;
        const int row = ti * BM + rl;
        float rsum = 0.f;
#pragma unroll
        for (int n = 0; n < 4; ++n) {
          const int cl = wc * 64 + fr + n * 16;
          float v = acc[m][n][j] * scale;
          v = fminf(fmaxf(v, -1.0e9f), 1.0e9f);  // CLAMP
          v = fminf(v, 60.0f);                   // overflow guard
          float e = __expf(v - 5.0f);
          if (diag && cl < rl) e = 0.f;
          rsum += e;
          ((u16*)Cp)[cbase + (size_t)row * LDC + ocol0 + n * 16] = f2bf(e);
        }
        rsum += __shfl_xor(rsum, 1, 64);
        rsum += __shfl_xor(rsum, 2, 64);
        rsum += __shfl_xor(rsum, 4, 64);
        rsum += __shfl_xor(rsum, 8, 64);
        if (fr == 0) slds[rl * 4 + wc] = rsum;
      }
    }
    __syncthreads();
    if (tid < 256) {
      float t = slds[tid * 4 + 0] + slds[tid * 4 + 1] +
                slds[tid * 4 + 2] + slds[tid * 4 + 3];
      sumP[ti * BM + tid] = t;
    }
  } else {
#pragma unroll
    for (int m = 0; m < FM; ++m) {
#pragma unroll
      for (int j = 0; j < 4; ++j) {
        const int row = orow0 + m * 16 + j;
        float mul = (EPI == 2) ? invRow[row] : 1.0f;
#pragma unroll
        for (int n = 0; n < 4; ++n) {
          const int col = ocol0 + n * 16;
          const float bv = bias ? bias[col] : 0.0f;
          const size_t idx = cbase + (size_t)row * LDC + col;
          if constexpr (EPI == 2) {
            ((float*)Cp)[idx] = acc[m][n][j] * mul + bv;
          } else {
            ((u16*)Cp)[idx] = f2bf(acc[m][n][j] + bv);
          }
        }
      }
    }
  }
#undef GLL
#undef STAGE_A
#undef STAGE_B
#undef DS_A
#undef DS_B
#undef MMA
#undef BAR
#undef LGKM0
#undef VMN
#undef VM0
#undef PRIO1
#undef PRIO0
}

// ---------------- combined Wt + QK^T dispatch (both BM=256) -----------------
// QK part: batch -> XCD affinity (bzl = q % nb): per-XCD Q/K set = 1 batch.
__global__ __launch_bounds__(512, 2) void gemm_qkwt(
    const u16* __restrict__ QKVp, const u16* __restrict__ w0t,
    u16* __restrict__ Wt, u16* __restrict__ sc, float* __restrict__ sumP,
    int wtBlocks, int b0, int nb, float qk_scale) {
  __shared__ u16 As[2][256 * 64];
  __shared__ u16 Bs[2][256 * 64];
  const long long sQKV = 2048LL * 3072, sWt = 1024LL * 2048, sS = 2048LL * 2048;
  int x = blockIdx.x;
  if (x < wtBlocks) {
    int r = x & 7, o = x >> 3;
    int ti = o & 3, bztj = r + 8 * (o >> 2);
    int bz = bztj >> 3, tj = bztj & 7;
    gemm_body<256, 0, 1024, 3072, 2048, 1024, 0>(
        w0t, QKVp + (size_t)bz * sQKV + 2048, Wt, nullptr, 0, 1.0f,
        (size_t)bz * sWt, ti, tj, &As[0][0], &Bs[0][0], nullptr, 0, nullptr);
  } else {
    int q = x - wtBlocks;
    int bzl = q % nb, t36 = q / nb;
    int bz = b0 + bzl;
    int tj = 0, accm = 0;
    while (t36 >= accm + tj + 1) { accm += tj + 1; ++tj; }
    int tq = t36 - accm;
    const u16* Ab = QKVp + (size_t)bz * sQKV;
    gemm_body<256, 1, 3072, 3072, 2048, 1024, 0>(
        Ab, Ab + 1024, sc, nullptr, 0, qk_scale, (size_t)bzl * sS,
        tq, tj, &As[0][0], &Bs[0][0],
        sumP + ((size_t)bz * 8 + tj) * 2048, tq == tj, nullptr);
  }
}

// ---------------- PV dispatch (BM=128), batch->XCD + LPT ti-major -----------
__global__ __launch_bounds__(512, 2) void gemm_pv(
    const u16* __restrict__ sc, const u16* __restrict__ Wt,
    float* __restrict__ out, const float* __restrict__ b0v,
    const float* __restrict__ inv, int nb, int bA) {
  __shared__ u16 As[2][128 * 64];
  __shared__ u16 Bs[2][256 * 64];
  const long long sP = 2048LL * 2048, sWt = 1024LL * 2048, sH = 2048LL * 1024;
  int x = blockIdx.x;
  int bzl = x % nb;        // batch -> XCD affinity (Wt/P set per XCD)
  int rem = x / nb;        // 0..63, ascending ti = heavy blocks first (LPT)
  int ti = rem >> 2, tj = rem & 3;
  int bz = bA + bzl;
  gemm_body<128, 2, 2048, 2048, 1024, 2048, -1>(
      sc + (size_t)bzl * sP, Wt + (size_t)bz * sWt, out, b0v, ti * 128, 1.0f,
      (size_t)bz * sH, ti, tj, &As[0][0], &Bs[0][0], nullptr, 0,
      inv + (size_t)bz * 2048);
}

extern "C" void kernel_launch(void* const* d_in, const int* in_sizes, int n_in,
                              void* d_out, int out_size, void* d_ws, size_t ws_size,
                              hipStream_t stream) {
  (void)in_sizes; (void)n_in; (void)out_size;
  const float* x   = (const float*)d_in[0];
  const float* lnw = (const float*)d_in[1];
  const float* lnb = (const float*)d_in[2];
  const float* wq  = (const float*)d_in[3];
  const float* bq  = (const float*)d_in[4];
  const float* wk  = (const float*)d_in[5];
  const float* bk  = (const float*)d_in[6];
  const float* wv  = (const float*)d_in[7];
  const float* bv  = (const float*)d_in[8];
  const float* w0  = (const float*)d_in[9];
  const float* b0  = (const float*)d_in[10];
  float* out = (float*)d_out;

  const size_t ROWS = 16384;  // B*S
  char* ws = (char*)d_ws;
  size_t off = 0;
  auto alloc = [&](size_t bytes) -> void* {
    void* p = ws + off;
    off += (bytes + 255) & ~(size_t)255;
    return p;
  };
  u16*   xn    = (u16*)alloc(ROWS * 1024 * 2);          // 32 MB
  u16*   wqkvt = (u16*)alloc((size_t)3072 * 1024 * 2);  // 6 MB
  u16*   w0t   = (u16*)alloc((size_t)1024 * 1024 * 2);  // 2 MB
  float* bqkv  = (float*)alloc(3072 * 4);
  float* sumP  = (float*)alloc((size_t)8 * 8 * 2048 * 4);  // 512 KB
  float* inv   = (float*)alloc((size_t)8 * 2048 * 4);      // 64 KB
  u16*   QKV   = (u16*)alloc(ROWS * 3072 * 2);          // ~100.7 MB
  u16*   Wt    = (u16*)alloc(ROWS * 1024 * 2);          // 32 MB [8][1024][2048]

  // scores (E bf16): NBCH batches of [2048 x 2048] per pass (8 MB each)
  const size_t CHUNK1 = (size_t)2048 * 2048 * 2;
  size_t avail = (ws_size > off) ? ws_size - off : 0;
  int NBCH = (int)(avail / CHUNK1);
  if (NBCH > 8) NBCH = 8;
  if (NBCH < 1) NBCH = 1;
  u16* sc = (u16*)(ws + off);

  ln_kernel<<<dim3(16384), dim3(256), 0, stream>>>(x, lnw, lnb, xn);
  dim3 tb(32, 8);
  transpose_w<<<dim3(32, 32), tb, 0, stream>>>(wq, wqkvt, 1024, 1024);
  transpose_w<<<dim3(32, 32), tb, 0, stream>>>(wk, wqkvt + (size_t)1024 * 1024, 1024, 1024);
  transpose_w<<<dim3(32, 32), tb, 0, stream>>>(wv, wqkvt + (size_t)2048 * 1024, 1024, 1024);
  transpose_w<<<dim3(32, 32), tb, 0, stream>>>(w0, w0t, 1024, 1024);
  concat_bias<<<dim3(3), dim3(1024), 0, stream>>>(bq, bk, bv, bqkv);

  // Fused QKV projection via the R3-verbatim kernel (measured 118.7 us)
  gemm256<0, 0><<<dim3(12, 64, 1), dim3(512), 0, stream>>>(
      xn, wqkvt, QKV, bqkv, 1024, 1024, 1024, 3072, 1.0f, 0, 0, 0);

  float qk_scale = (float)(1.0 / (std::sqrt(1024.0) + 1e-9));

  for (int bA = 0; bA < 8; bA += NBCH) {
    int nb = 8 - bA;
    if (nb > NBCH) nb = NBCH;
    int wtB = (bA == 0) ? 256 : 0;  // Wt for ALL batches rides the first pass
    gemm_qkwt<<<dim3(wtB + nb * 36), dim3(512), 0, stream>>>(
        QKV, w0t, Wt, sc, sumP, wtB, bA, nb, qk_scale);
    rowinv_kernel<<<dim3(nb * 8), dim3(256), 0, stream>>>(sumP, inv, bA);
    gemm_pv<<<dim3(64 * nb), dim3(512), 0, stream>>>(
        sc, Wt, out, b0, inv, nb, bA);
  }
}

// Round 11
// 304.672 us; speedup vs baseline: 1.1597x; 1.0679x over previous
//
#include <hip/hip_runtime.h>
#include <cmath>

using u16 = unsigned short;
using u32 = unsigned int;
using bf16x8 = __attribute__((ext_vector_type(8))) __bf16;
using f32x4  = __attribute__((ext_vector_type(4))) float;

__device__ inline u16 f2bf(float f) {
  u32 u = __float_as_uint(f);
  u32 r = (u + 0x7fffu + ((u >> 16) & 1u)) >> 16;  // RNE
  return (u16)r;
}

// ---------------- LayerNorm: x[row][1024] f32 -> xn bf16 ----------------
__global__ __launch_bounds__(256) void ln_kernel(
    const float* __restrict__ x, const float* __restrict__ w,
    const float* __restrict__ b, u16* __restrict__ xn) {
  int row = blockIdx.x;
  const float4* xr = (const float4*)(x + (size_t)row * 1024);
  float4 v = xr[threadIdx.x];
  float s  = v.x + v.y + v.z + v.w;
  float ss = v.x * v.x + v.y * v.y + v.z * v.z + v.w * v.w;
  int lane = threadIdx.x & 63, wave = threadIdx.x >> 6;
#pragma unroll
  for (int o = 32; o >= 1; o >>= 1) {
    s  += __shfl_xor(s, o, 64);
    ss += __shfl_xor(ss, o, 64);
  }
  __shared__ float rs[4], rq[4];
  if (lane == 0) { rs[wave] = s; rq[wave] = ss; }
  __syncthreads();
  s  = rs[0] + rs[1] + rs[2] + rs[3];
  ss = rq[0] + rq[1] + rq[2] + rq[3];
  float mean = s * (1.0f / 1024.0f);
  float var  = ss * (1.0f / 1024.0f) - mean * mean;
  float rstd = rsqrtf(var + 1e-5f);
  int c = threadIdx.x * 4;
  ushort4 ov;
  ov.x = f2bf((v.x - mean) * rstd * w[c + 0] + b[c + 0]);
  ov.y = f2bf((v.y - mean) * rstd * w[c + 1] + b[c + 1]);
  ov.z = f2bf((v.z - mean) * rstd * w[c + 2] + b[c + 2]);
  ov.w = f2bf((v.w - mean) * rstd * w[c + 3] + b[c + 3]);
  ((ushort4*)(xn + (size_t)row * 1024))[threadIdx.x] = ov;
}

// ------- fused weight transpose: z in {wq,wk,wv,w0}, f32[1024][1024]->bf16^T --
__global__ __launch_bounds__(256) void transpose_w4(
    const float* __restrict__ wq, const float* __restrict__ wk,
    const float* __restrict__ wv, const float* __restrict__ w0,
    u16* __restrict__ wqkvt, u16* __restrict__ w0t) {
  int z = blockIdx.z;
  const float* in = (z == 0) ? wq : (z == 1) ? wk : (z == 2) ? wv : w0;
  u16* out = (z < 3) ? (wqkvt + (size_t)z * 1024 * 1024) : w0t;
  __shared__ float tile[32][33];
  int c0 = blockIdx.x * 32, r0 = blockIdx.y * 32;
  int tx = threadIdx.x, ty = threadIdx.y;  // block (32,8)
#pragma unroll
  for (int i = 0; i < 32; i += 8)
    tile[ty + i][tx] = in[(size_t)(r0 + ty + i) * 1024 + c0 + tx];
  __syncthreads();
#pragma unroll
  for (int i = 0; i < 32; i += 8)
    out[(size_t)(c0 + ty + i) * 1024 + r0 + tx] = f2bf(tile[tx][ty + i]);
}

// ---------------- bias concat: bq|bk|bv -> bqkv[3072] ----------------
__global__ void concat_bias(const float* __restrict__ bq, const float* __restrict__ bk,
                            const float* __restrict__ bv, float* __restrict__ o) {
  int i = blockIdx.x * 1024 + threadIdx.x;
  const float* src = (blockIdx.x == 0) ? bq : (blockIdx.x == 1) ? bk : bv;
  o[i] = src[threadIdx.x];
}

// ============== R3-VERBATIM 256x256 8-phase bf16 GEMM (measured 118.7 us) ====
// Used ONLY for the QKV projection (rule #19: do not touch this source form).
template <int OUTF32, int MODE>
__global__ __launch_bounds__(512, 2) void gemm256(
    const u16* __restrict__ A, const u16* __restrict__ B, void* __restrict__ Cv,
    const float* __restrict__ bias, int K, int lda, int ldb, int ldc,
    float scale, long long sA, long long sB, long long sC) {
  // XCD-aware bijective swizzle of (x,y) linear index
  int gx = gridDim.x;
  int wg = blockIdx.y * gx + blockIdx.x;
  {
    int nwg = gx * gridDim.y;
    if ((nwg & 7) == 0) {
      int q = nwg >> 3;
      wg = (wg & 7) * q + (wg >> 3);
    }
  }
  const int ti = wg / gx, tj = wg % gx, bz = blockIdx.z;
  if (MODE == 1 && tj < ti) return;

  const u16* Ab = A + (size_t)bz * (size_t)sA;
  const u16* Bb = B + (size_t)bz * (size_t)sB;

  __shared__ u16 As[2][256 * 64];  // 64 KiB
  __shared__ u16 Bs[2][256 * 64];  // 64 KiB

  const int tid = threadIdx.x;
  const int wave = tid >> 6, lane = tid & 63;
  const int wr = wave >> 2, wc = wave & 3;  // 2 x 4 wave grid
  const int fr = lane & 15;
  const int kb16 = (lane >> 4) * 16;
  const int swz = (fr & 7) << 4;
  const int cs0 = kb16 ^ swz;
  const int cs1 = (64 + kb16) ^ swz;
  const int aRowOff = (wr * 128 + fr) * 128;
  const int bRowOff = (wc * 64 + fr) * 128;

  size_t gAo[2][2], gBo[2][2];
  u32 ldsA[2][2], ldsB[2][2];
#pragma unroll
  for (int h = 0; h < 2; ++h) {
#pragma unroll
    for (int l = 0; l < 2; ++l) {
      int i = l * 512 + tid;
      int rih = i >> 3, ch8 = i & 7;
      int rA = (rih & 63) + ((rih >> 6) << 7) + h * 64;
      int cbA = (ch8 << 4) ^ ((rA & 7) << 4);
      gAo[h][l] = (size_t)rA * lda + (cbA >> 1);
      ldsA[h][l] = (u32)(rA * 8 + ch8) * 16;
      int rB = (rih & 31) + ((rih >> 5) << 6) + h * 32;
      int cbB = (ch8 << 4) ^ ((rB & 7) << 4);
      gBo[h][l] = (size_t)rB * ldb + (cbB >> 1);
      ldsB[h][l] = (u32)(rB * 8 + ch8) * 16;
    }
  }
  const size_t aBase = (size_t)(ti * 256) * lda;
  const size_t bBase = (size_t)(tj * 256) * ldb;

  const int k0 = (MODE == 2) ? ti * 256 : 0;
  const int niter = (K - k0) / 128;

  f32x4 acc[8][4] = {};
  bf16x8 aF[4][2], bF[4][2];

#define GLL(gaddr, laddr)                                        \
  __builtin_amdgcn_global_load_lds(                              \
      (const __attribute__((address_space(1))) void*)(gaddr),    \
      (__attribute__((address_space(3))) void*)(laddr), 16, 0, 0)

#define STAGE_A(buf, h, t)                                                     \
  do {                                                                         \
    const size_t _kt = aBase + (size_t)(k0 + (t) * 64);                        \
    GLL(Ab + _kt + gAo[h][0], (char*)&As[buf][0] + ldsA[h][0]);                \
    GLL(Ab + _kt + gAo[h][1], (char*)&As[buf][0] + ldsA[h][1]);                \
  } while (0)
#define STAGE_B(buf, h, t)                                                     \
  do {                                                                         \
    const size_t _kt = bBase + (size_t)(k0 + (t) * 64);                        \
    GLL(Bb + _kt + gBo[h][0], (char*)&Bs[buf][0] + ldsB[h][0]);                \
    GLL(Bb + _kt + gBo[h][1], (char*)&Bs[buf][0] + ldsB[h][1]);                \
  } while (0)

#define DS_A(buf, qm)                                                \
  do {                                                               \
    const char* _pa = (const char*)&As[buf][0] + aRowOff + (qm)*8192;\
    _Pragma("unroll") for (int mm = 0; mm < 4; ++mm) {               \
      aF[mm][0] = *(const bf16x8*)(_pa + mm * 2048 + cs0);           \
      aF[mm][1] = *(const bf16x8*)(_pa + mm * 2048 + cs1);           \
    }                                                                \
  } while (0)
#define DS_B(buf, nh)                                                \
  do {                                                               \
    const char* _pb = (const char*)&Bs[buf][0] + bRowOff;            \
    _Pragma("unroll") for (int nn = 0; nn < 2; ++nn) {               \
      bF[(nh)*2 + nn][0] = *(const bf16x8*)(_pb + ((nh)*2 + nn) * 2048 + cs0); \
      bF[(nh)*2 + nn][1] = *(const bf16x8*)(_pb + ((nh)*2 + nn) * 2048 + cs1); \
    }                                                                \
  } while (0)

#define MMA(qm, nh)                                                          \
  do {                                                                       \
    _Pragma("unroll") for (int mm = 0; mm < 4; ++mm)                         \
    _Pragma("unroll") for (int nn = 0; nn < 2; ++nn) {                       \
      f32x4 _c = acc[(qm)*4 + mm][(nh)*2 + nn];                              \
      _c = __builtin_amdgcn_mfma_f32_16x16x32_bf16(aF[mm][0], bF[(nh)*2+nn][0], _c, 0, 0, 0); \
      _c = __builtin_amdgcn_mfma_f32_16x16x32_bf16(aF[mm][1], bF[(nh)*2+nn][1], _c, 0, 0, 0); \
      acc[(qm)*4 + mm][(nh)*2 + nn] = _c;                                    \
    }                                                                        \
  } while (0)

#define BAR __builtin_amdgcn_s_barrier()
#define LGKM0 asm volatile("s_waitcnt lgkmcnt(0)" ::: "memory")
#define VM6 asm volatile("s_waitcnt vmcnt(6)" ::: "memory")
#define VM0 asm volatile("s_waitcnt vmcnt(0)" ::: "memory")
#define PRIO1 __builtin_amdgcn_s_setprio(1)
#define PRIO0 __builtin_amdgcn_s_setprio(0)

  STAGE_B(0, 0, 0); STAGE_B(0, 1, 0); STAGE_A(0, 0, 0); STAGE_A(0, 1, 0);
  STAGE_B(1, 0, 1); STAGE_B(1, 1, 1); STAGE_A(1, 0, 1);
  VM6; BAR;

  for (int it = 0; it < niter; ++it) {
    const bool last = (it == niter - 1);
    const int t1g = 2 * it + 1, t2g = 2 * it + 2, t3g = 2 * it + 3;

    DS_A(0, 0); DS_B(0, 0);
    STAGE_A(1, 1, t1g);
    BAR; LGKM0; PRIO1; MMA(0, 0); PRIO0; BAR;
    DS_B(0, 1);
    if (!last) STAGE_B(0, 0, t2g);
    BAR; LGKM0; PRIO1; MMA(0, 1); PRIO0; BAR;
    DS_A(0, 1);
    if (!last) STAGE_B(0, 1, t2g);
    BAR; LGKM0; PRIO1; MMA(1, 0); PRIO0; BAR;
    if (!last) STAGE_A(0, 0, t2g);
    BAR; PRIO1; MMA(1, 1); PRIO0;
    if (last) { VM0; } else { VM6; }
    BAR;
    DS_A(1, 0); DS_B(1, 0);
    if (!last) STAGE_A(0, 1, t2g);
    BAR; LGKM0; PRIO1; MMA(0, 0); PRIO0; BAR;
    DS_B(1, 1);
    if (!last) STAGE_B(1, 0, t3g);
    BAR; LGKM0; PRIO1; MMA(0, 1); PRIO0; BAR;
    DS_A(1, 1);
    if (!last) STAGE_B(1, 1, t3g);
    BAR; LGKM0; PRIO1; MMA(1, 0); PRIO0; BAR;
    if (!last) STAGE_A(1, 0, t3g);
    BAR; PRIO1; MMA(1, 1); PRIO0;
    if (!last) VM6;
    BAR;
  }

  const int orow0 = ti * 256 + wr * 128 + ((lane >> 4) << 2);
  const int ocol0 = tj * 256 + wc * 64 + fr;
#pragma unroll
  for (int m = 0; m < 8; ++m) {
#pragma unroll
    for (int n = 0; n < 4; ++n) {
      const int col = ocol0 + n * 16;
      const float bv = bias ? bias[col] : 0.0f;
#pragma unroll
      for (int j = 0; j < 4; ++j) {
        const int row = orow0 + m * 16 + j;
        const float v = acc[m][n][j] * scale + bv;
        const size_t idx = (size_t)bz * (size_t)sC + (size_t)row * ldc + col;
        if (OUTF32) ((float*)Cv)[idx] = v;
        else        ((u16*)Cv)[idx]   = f2bf(v);
      }
    }
  }
#undef GLL
#undef STAGE_A
#undef STAGE_B
#undef DS_A
#undef DS_B
#undef MMA
#undef BAR
#undef LGKM0
#undef VM6
#undef VM0
#undef PRIO1
#undef PRIO0
}

// ---------------- BMx256 8-phase body (QK / Wt / PV paths) ------------------
// EPI 0: bf16 out (+bias). EPI 1: QK — E=exp(clamp(v)*scale-5), diag mask,
// bf16 store + per-row partial sums -> sumP. EPI 2: PV — f32 = acc*inv + bias,
// inv computed in-kernel from sumP partials (rowinv pass eliminated).
template <int BM, int EPI, int LDA, int LDB, int LDC, int KK, int K0CT>
__device__ __forceinline__ void gemm_body(
    const u16* __restrict__ Ab, const u16* __restrict__ Bb,
    void* __restrict__ Cp, const float* __restrict__ bias,
    int rk0, float scale, size_t cbase, int ti, int tj,
    u16* __restrict__ AsP, u16* __restrict__ BsP,
    float* __restrict__ sumP, int diag) {
  constexpr int WM = BM / 2;
  constexpr int MH = BM / 64;
  constexpr int FM = 2 * MH;
  constexpr int HR = BM / 4;
  constexpr int LA = BM / 128;

  const int k0 = (K0CT >= 0) ? K0CT : rk0;

  const int tid = threadIdx.x;
  const int wave = tid >> 6, lane = tid & 63;
  const int wr = wave >> 2, wc = wave & 3;
  const int fr = lane & 15;
  const int kb16 = (lane >> 4) * 16;
  const int swz = (fr & 7) << 4;
  const int cs0 = kb16 ^ swz;
  const int cs1 = (64 + kb16) ^ swz;
  const int aRowOff = (wr * WM + fr) * 128;
  const int bRowOff = (wc * 64 + fr) * 128;

  // EPI2: fold rowinv — inv for this block's BM rows from sumP partials.
  __shared__ float invLds[(EPI == 2) ? BM : 1];
  if constexpr (EPI == 2) {
    if (tid < BM) {
      int s = ti * BM + tid;
      float a = 0.f;
      for (int q2 = s >> 8; q2 < 8; ++q2) a += sumP[q2 * 2048 + s];
      invLds[tid] = 1.0f / a;
    }
  }

  size_t gAo[2][LA], gBo[2][2];
  u32 ldsA[2][LA], ldsB[2][2];
#pragma unroll
  for (int h = 0; h < 2; ++h) {
#pragma unroll
    for (int l = 0; l < LA; ++l) {
      int i = l * 512 + tid;
      int rih = i >> 3, ch8 = i & 7;
      int rA = (rih % HR) + (rih / HR) * WM + h * HR;
      int cbA = (ch8 << 4) ^ ((rA & 7) << 4);
      gAo[h][l] = (size_t)rA * LDA + (cbA >> 1);
      ldsA[h][l] = (u32)(rA * 8 + ch8) * 16;
    }
#pragma unroll
    for (int l = 0; l < 2; ++l) {
      int i = l * 512 + tid;
      int rih = i >> 3, ch8 = i & 7;
      int rB = (rih & 31) + ((rih >> 5) << 6) + h * 32;
      int cbB = (ch8 << 4) ^ ((rB & 7) << 4);
      gBo[h][l] = (size_t)rB * LDB + (cbB >> 1);
      ldsB[h][l] = (u32)(rB * 8 + ch8) * 16;
    }
  }
  const size_t aBase = (size_t)(ti * BM) * LDA;
  const size_t bBase = (size_t)(tj * 256) * LDB;
  const int niter = (KK - k0) / 128;

  f32x4 acc[FM][4] = {};
  bf16x8 aF[MH][2], bF[4][2];

#define GLL(gaddr, laddr)                                        \
  __builtin_amdgcn_global_load_lds(                              \
      (const __attribute__((address_space(1))) void*)(gaddr),    \
      (__attribute__((address_space(3))) void*)(laddr), 16, 0, 0)

#define STAGE_A(buf, h, t)                                                   \
  do {                                                                       \
    const size_t _kt = aBase + (size_t)(k0 + (t) * 64);                      \
    _Pragma("unroll") for (int _l = 0; _l < LA; ++_l)                        \
        GLL(Ab + _kt + gAo[h][_l],                                           \
            (char*)(AsP + (buf) * (BM * 64)) + ldsA[h][_l]);                 \
  } while (0)
#define STAGE_B(buf, h, t)                                                   \
  do {                                                                       \
    const size_t _kt = bBase + (size_t)(k0 + (t) * 64);                      \
    _Pragma("unroll") for (int _l = 0; _l < 2; ++_l)                         \
        GLL(Bb + _kt + gBo[h][_l],                                           \
            (char*)(BsP + (buf) * (256 * 64)) + ldsB[h][_l]);                \
  } while (0)

#define DS_A(buf, qm)                                                        \
  do {                                                                       \
    const char* _pa =                                                        \
        (const char*)(AsP + (buf) * (BM * 64)) + aRowOff + (qm) * (MH * 2048); \
    _Pragma("unroll") for (int mm = 0; mm < MH; ++mm) {                      \
      aF[mm][0] = *(const bf16x8*)(_pa + mm * 2048 + cs0);                   \
      aF[mm][1] = *(const bf16x8*)(_pa + mm * 2048 + cs1);                   \
    }                                                                        \
  } while (0)
#define DS_B(buf, nh)                                                        \
  do {                                                                       \
    const char* _pb = (const char*)(BsP + (buf) * (256 * 64)) + bRowOff;     \
    _Pragma("unroll") for (int nn = 0; nn < 2; ++nn) {                       \
      bF[(nh)*2 + nn][0] = *(const bf16x8*)(_pb + ((nh)*2 + nn) * 2048 + cs0); \
      bF[(nh)*2 + nn][1] = *(const bf16x8*)(_pb + ((nh)*2 + nn) * 2048 + cs1); \
    }                                                                        \
  } while (0)

#define MMA(qm, nh)                                                          \
  do {                                                                       \
    _Pragma("unroll") for (int mm = 0; mm < MH; ++mm)                        \
    _Pragma("unroll") for (int nn = 0; nn < 2; ++nn) {                       \
      f32x4 _c = acc[(qm)*MH + mm][(nh)*2 + nn];                             \
      _c = __builtin_amdgcn_mfma_f32_16x16x32_bf16(aF[mm][0], bF[(nh)*2+nn][0], _c, 0, 0, 0); \
      _c = __builtin_amdgcn_mfma_f32_16x16x32_bf16(aF[mm][1], bF[(nh)*2+nn][1], _c, 0, 0, 0); \
      acc[(qm)*MH + mm][(nh)*2 + nn] = _c;                                   \
    }                                                                        \
  } while (0)

#define BAR __builtin_amdgcn_s_barrier()
#define LGKM0 asm volatile("s_waitcnt lgkmcnt(0)" ::: "memory")
#define VMN                                                                  \
  do {                                                                       \
    if constexpr (BM == 256)                                                 \
      asm volatile("s_waitcnt vmcnt(6)" ::: "memory");                       \
    else                                                                     \
      asm volatile("s_waitcnt vmcnt(5)" ::: "memory");                       \
  } while (0)
#define VM0 asm volatile("s_waitcnt vmcnt(0)" ::: "memory")
#define PRIO1 __builtin_amdgcn_s_setprio(1)
#define PRIO0 __builtin_amdgcn_s_setprio(0)

  STAGE_B(0, 0, 0); STAGE_B(0, 1, 0); STAGE_A(0, 0, 0); STAGE_A(0, 1, 0);
  STAGE_B(1, 0, 1); STAGE_B(1, 1, 1); STAGE_A(1, 0, 1);
  VMN; BAR;

#pragma unroll 1
  for (int it = 0; it < niter; ++it) {
    const bool last = (it == niter - 1);
    const int t1g = 2 * it + 1, t2g = 2 * it + 2, t3g = 2 * it + 3;

    DS_A(0, 0); DS_B(0, 0);
    STAGE_A(1, 1, t1g);
    BAR; LGKM0; PRIO1; MMA(0, 0); PRIO0; BAR;
    DS_B(0, 1);
    if (!last) STAGE_B(0, 0, t2g);
    BAR; LGKM0; PRIO1; MMA(0, 1); PRIO0; BAR;
    DS_A(0, 1);
    if (!last) STAGE_B(0, 1, t2g);
    BAR; LGKM0; PRIO1; MMA(1, 0); PRIO0; BAR;
    if (!last) STAGE_A(0, 0, t2g);
    BAR; PRIO1; MMA(1, 1); PRIO0;
    if (last) { VM0; } else { VMN; }
    BAR;
    DS_A(1, 0); DS_B(1, 0);
    if (!last) STAGE_A(0, 1, t2g);
    BAR; LGKM0; PRIO1; MMA(0, 0); PRIO0; BAR;
    DS_B(1, 1);
    if (!last) STAGE_B(1, 0, t3g);
    BAR; LGKM0; PRIO1; MMA(0, 1); PRIO0; BAR;
    DS_A(1, 1);
    if (!last) STAGE_B(1, 1, t3g);
    BAR; LGKM0; PRIO1; MMA(1, 0); PRIO0; BAR;
    if (!last) STAGE_A(1, 0, t3g);
    BAR; PRIO1; MMA(1, 1); PRIO0;
    if (!last) VMN;
    BAR;
  }

  const int orowL = wr * WM + ((lane >> 4) << 2);
  const int orow0 = ti * BM + orowL;
  const int ocol0 = tj * 256 + wc * 64 + fr;

  if constexpr (EPI == 1) {
    float* slds = (float*)AsP;  // [BM][4] cross-wave reduce buffer
#pragma unroll
    for (int m = 0; m < FM; ++m) {
#pragma unroll
      for (int j = 0; j < 4; ++j) {
        const int rl = orowL + m * 16 + j;
        const int row = ti * BM + rl;
        float rsum = 0.f;
#pragma unroll
        for (int n = 0; n < 4; ++n) {
          const int cl = wc * 64 + fr + n * 16;
          float v = acc[m][n][j] * scale;
          v = fminf(fmaxf(v, -1.0e9f), 1.0e9f);  // CLAMP
          v = fminf(v, 60.0f);                   // overflow guard
          float e = __expf(v - 5.0f);
          if (diag && cl < rl) e = 0.f;
          rsum += e;
          ((u16*)Cp)[cbase + (size_t)row * LDC + ocol0 + n * 16] = f2bf(e);
        }
        rsum += __shfl_xor(rsum, 1, 64);
        rsum += __shfl_xor(rsum, 2, 64);
        rsum += __shfl_xor(rsum, 4, 64);
        rsum += __shfl_xor(rsum, 8, 64);
        if (fr == 0) slds[rl * 4 + wc] = rsum;
      }
    }
    __syncthreads();
    if (tid < BM) {
      float t = slds[tid * 4 + 0] + slds[tid * 4 + 1] +
                slds[tid * 4 + 2] + slds[tid * 4 + 3];
      sumP[ti * BM + tid] = t;
    }
  } else {
#pragma unroll
    for (int m = 0; m < FM; ++m) {
#pragma unroll
      for (int j = 0; j < 4; ++j) {
        const int row = orow0 + m * 16 + j;
        float mul = (EPI == 2) ? invLds[orowL + m * 16 + j] : 1.0f;
#pragma unroll
        for (int n = 0; n < 4; ++n) {
          const int col = ocol0 + n * 16;
          const float bv = bias ? bias[col] : 0.0f;
          const size_t idx = cbase + (size_t)row * LDC + col;
          if constexpr (EPI == 2) {
            ((float*)Cp)[idx] = acc[m][n][j] * mul + bv;
          } else {
            ((u16*)Cp)[idx] = f2bf(acc[m][n][j] + bv);
          }
        }
      }
    }
  }
#undef GLL
#undef STAGE_A
#undef STAGE_B
#undef DS_A
#undef DS_B
#undef MMA
#undef BAR
#undef LGKM0
#undef VMN
#undef VM0
#undef PRIO1
#undef PRIO0
}

// ---- combined QK^T (BM=256, first, LPT) + Wt (BM=128, half-cost filler) ----
// QK: batch->XCD affinity; triangular decode. Wt: bz->XCD, ti-fastest.
__global__ __launch_bounds__(512, 2) void gemm_qkwt(
    const u16* __restrict__ QKVp, const u16* __restrict__ w0t,
    u16* __restrict__ Wt, u16* __restrict__ sc, float* __restrict__ sumP,
    int qkBlocks, int b0, int nb, float qk_scale) {
  __shared__ u16 As[2][256 * 64];
  __shared__ u16 Bs[2][256 * 64];
  const long long sQKV = 2048LL * 3072, sWt = 1024LL * 2048, sS = 2048LL * 2048;
  int x = blockIdx.x;
  if (x < qkBlocks) {
    int bzl = x % nb, t36 = x / nb;
    int bz = b0 + bzl;
    int tj = 0, accm = 0;
    while (t36 >= accm + tj + 1) { accm += tj + 1; ++tj; }
    int tq = t36 - accm;
    const u16* Ab = QKVp + (size_t)bz * sQKV;
    gemm_body<256, 1, 3072, 3072, 2048, 1024, 0>(
        Ab, Ab + 1024, sc, nullptr, 0, qk_scale, (size_t)bzl * sS,
        tq, tj, &As[0][0], &Bs[0][0],
        sumP + ((size_t)bz * 8 + tj) * 2048, tq == tj);
  } else {
    int x2 = x - qkBlocks;           // 0..511
    int bz = x2 & 7;                 // XCD affinity
    int o = x2 >> 3;                 // 0..63
    int ti = o & 7, tj = o >> 3;     // ti-fastest: 8 V-slice sharers adjacent
    gemm_body<128, 0, 1024, 3072, 2048, 1024, 0>(
        w0t, QKVp + (size_t)bz * sQKV + 2048, Wt, nullptr, 0, 1.0f,
        (size_t)bz * sWt, ti, tj, &As[0][0], &Bs[0][0], nullptr, 0);
  }
}

// ---------------- PV dispatch (BM=128), batch->XCD + LPT; inv folded --------
__global__ __launch_bounds__(512, 2) void gemm_pv(
    const u16* __restrict__ sc, const u16* __restrict__ Wt,
    float* __restrict__ out, const float* __restrict__ b0v,
    float* __restrict__ sumP, int nb, int bA) {
  __shared__ u16 As[2][128 * 64];
  __shared__ u16 Bs[2][256 * 64];
  const long long sP = 2048LL * 2048, sWt = 1024LL * 2048, sH = 2048LL * 1024;
  int x = blockIdx.x;
  int bzl = x % nb;        // batch -> XCD affinity
  int rem = x / nb;        // ascending ti = heavy blocks first (LPT)
  int ti = rem >> 2, tj = rem & 3;
  int bz = bA + bzl;
  gemm_body<128, 2, 2048, 2048, 1024, 2048, -1>(
      sc + (size_t)bzl * sP, Wt + (size_t)bz * sWt, out, b0v, ti * 128, 1.0f,
      (size_t)bz * sH, ti, tj, &As[0][0], &Bs[0][0],
      sumP + (size_t)bz * 8 * 2048, 0);
}

extern "C" void kernel_launch(void* const* d_in, const int* in_sizes, int n_in,
                              void* d_out, int out_size, void* d_ws, size_t ws_size,
                              hipStream_t stream) {
  (void)in_sizes; (void)n_in; (void)out_size;
  const float* x   = (const float*)d_in[0];
  const float* lnw = (const float*)d_in[1];
  const float* lnb = (const float*)d_in[2];
  const float* wq  = (const float*)d_in[3];
  const float* bq  = (const float*)d_in[4];
  const float* wk  = (const float*)d_in[5];
  const float* bk  = (const float*)d_in[6];
  const float* wv  = (const float*)d_in[7];
  const float* bv  = (const float*)d_in[8];
  const float* w0  = (const float*)d_in[9];
  const float* b0  = (const float*)d_in[10];
  float* out = (float*)d_out;

  const size_t ROWS = 16384;  // B*S
  char* ws = (char*)d_ws;
  size_t off = 0;
  auto alloc = [&](size_t bytes) -> void* {
    void* p = ws + off;
    off += (bytes + 255) & ~(size_t)255;
    return p;
  };
  u16*   xn    = (u16*)alloc(ROWS * 1024 * 2);          // 32 MB
  u16*   wqkvt = (u16*)alloc((size_t)3072 * 1024 * 2);  // 6 MB
  u16*   w0t   = (u16*)alloc((size_t)1024 * 1024 * 2);  // 2 MB
  float* bqkv  = (float*)alloc(3072 * 4);
  float* sumP  = (float*)alloc((size_t)8 * 8 * 2048 * 4);  // 512 KB
  u16*   QKV   = (u16*)alloc(ROWS * 3072 * 2);          // ~100.7 MB
  u16*   Wt    = (u16*)alloc(ROWS * 1024 * 2);          // 32 MB [8][1024][2048]

  // scores (E bf16): NBCH batches of [2048 x 2048] per pass (8 MB each)
  const size_t CHUNK1 = (size_t)2048 * 2048 * 2;
  size_t avail = (ws_size > off) ? ws_size - off : 0;
  int NBCH = (int)(avail / CHUNK1);
  if (NBCH > 8) NBCH = 8;
  if (NBCH < 1) NBCH = 1;
  u16* sc = (u16*)(ws + off);

  ln_kernel<<<dim3(16384), dim3(256), 0, stream>>>(x, lnw, lnb, xn);
  transpose_w4<<<dim3(32, 32, 4), dim3(32, 8), 0, stream>>>(
      wq, wk, wv, w0, wqkvt, w0t);
  concat_bias<<<dim3(3), dim3(1024), 0, stream>>>(bq, bk, bv, bqkv);

  // Fused QKV projection via the R3-verbatim kernel
  gemm256<0, 0><<<dim3(12, 64, 1), dim3(512), 0, stream>>>(
      xn, wqkvt, QKV, bqkv, 1024, 1024, 1024, 3072, 1.0f, 0, 0, 0);

  float qk_scale = (float)(1.0 / (std::sqrt(1024.0) + 1e-9));

  for (int bA = 0; bA < 8; bA += NBCH) {
    int nb = 8 - bA;
    if (nb > NBCH) nb = NBCH;
    int qkB = nb * 36;
    int wtB = (bA == 0) ? 512 : 0;  // Wt (BM=128) for ALL batches, first pass
    gemm_qkwt<<<dim3(qkB + wtB), dim3(512), 0, stream>>>(
        QKV, w0t, Wt, sc, sumP, qkB, bA, nb, qk_scale);
    gemm_pv<<<dim3(64 * nb), dim3(512), 0, stream>>>(
        sc, Wt, out, b0, sumP, nb, bA);
  }
}